// Round 4
// baseline (159.832 us; speedup 1.0000x reference)
//
#include <hip/hip_runtime.h>

#define NB   1024
#define NT   256
#define BTOT 262144   // NB*NT == B

typedef __attribute__((ext_vector_type(8))) short short8;
typedef __attribute__((ext_vector_type(4))) float f32x4;

__device__ __forceinline__ float relu_(float x) { return fmaxf(x, 0.0f); }

__device__ __forceinline__ short f2bf(float x) {   // RNE f32->bf16
    unsigned u = __float_as_uint(x);
    unsigned r = (u + 0x7FFFu + ((u >> 16) & 1u)) >> 16;
    return (short)r;
}

// 144B rows; XOR-swizzle the 16B-block index with row&7 (blocks 0..7;
// block 8 = bytes 128..143 stays linear).
__device__ __forceinline__ unsigned swz(unsigned row, unsigned byteoff) {
    unsigned blk = byteoff >> 4, rest = byteoff & 15u;
    if (blk < 8u) blk ^= (row & 7u);
    return row * 144u + blk * 16u + rest;
}

// d_ws float-offset layout:
//   W1 0..179 | B1 180..189 | A0 190..199 | W2 200..599 | B2 600..619
//   W3 620..1819 | B3 1820..1849
// byte 7424:  fc1 frags (14*512 shorts)
// byte 21760: fc2 frags (12*512 shorts)
// byte 34048: partials [NB*12] f32
#define FR1_BYTE 7424
#define FR2_BYTE 21760
#define PART_BYTE 34048

__global__ __launch_bounds__(256) void kp_setup(
    const float* __restrict__ w1, const float* __restrict__ b1,
    const float* __restrict__ g1, const float* __restrict__ bt1,
    const float* __restrict__ m1, const float* __restrict__ v1,
    const float* __restrict__ w2, const float* __restrict__ b2,
    const float* __restrict__ g2, const float* __restrict__ bt2,
    const float* __restrict__ m2, const float* __restrict__ v2,
    const float* __restrict__ w3, const float* __restrict__ b3,
    const float* __restrict__ g3, const float* __restrict__ bt3,
    const float* __restrict__ m3, const float* __restrict__ v3,
    const float* __restrict__ fw1, const float* __restrict__ fw2,
    float* __restrict__ wsf, short* __restrict__ fr1, short* __restrict__ fr2)
{
    const int t = threadIdx.x;
    if (t < 10) {
        float s  = g1[t] * rsqrtf(v1[t] + 1e-5f);
        float bb = (b1[t] - m1[t]) * s + bt1[t];
        wsf[180 + t] = bb;
        wsf[190 + t] = relu_(bb);
        for (int i = 0; i < 18; ++i) wsf[t * 18 + i] = w1[t * 18 + i] * s;
    } else if (t >= 64 && t < 84) {
        int o = t - 64;
        float s = g2[o] * rsqrtf(v2[o] + 1e-5f);
        wsf[600 + o] = (b2[o] - m2[o]) * s + bt2[o];
        for (int i = 0; i < 20; ++i) wsf[200 + o * 20 + i] = w2[o * 20 + i] * s;
    } else if (t >= 128 && t < 158) {
        int o = t - 128;
        float s = g3[o] * rsqrtf(v3[o] + 1e-5f);
        wsf[1820 + o] = (b3[o] - m3[o]) * s + bt3[o];
        for (int i = 0; i < 40; ++i) wsf[620 + o * 40 + i] = w3[o * 40 + i] * s;
    }
    // fc1 B-frags: B1[k][j] = fw1[j*60+k]
    for (int e = t; e < 14 * 512; e += 256) {
        int pos = e >> 9, l = (e >> 3) & 63, j = e & 7;
        int n = pos >> 1, kt = pos & 1;
        int col = 16 * n + (l & 15);
        int k   = kt * 32 + (l >> 4) * 8 + j;
        float v = (col < 100 && k < 60) ? fw1[col * 60 + k] : 0.f;
        fr1[e] = f2bf(v);
    }
    // fc2 B-frags: B2[k][cc] = fw2[cc*100+k]
    for (int e = t; e < 12 * 512; e += 256) {
        int pos = e >> 9, l = (e >> 3) & 63, j = e & 7;
        int n = pos >> 2, kt = pos & 3;
        int col = 16 * n + (l & 15);
        int k   = kt * 32 + (l >> 4) * 8 + j;
        float v = (col < 36 && k < 100) ? fw2[col * 100 + k] : 0.f;
        fr2[e] = f2bf(v);
    }
}

__global__ __launch_bounds__(NT, 4) void kp_fwd(
    const float* __restrict__ cin, const int* __restrict__ tmask,
    const float* __restrict__ wf,          // folded weights (uniform -> s_load)
    const short* __restrict__ fr1,         // fc1 B-frags
    const short* __restrict__ fr2,         // fc2 B-frags
    const float* __restrict__ fb1, const float* __restrict__ fb2,
    float* __restrict__ xout, float* __restrict__ missout,
    float* __restrict__ partials)
{
    __shared__ __align__(16) unsigned char sAB[NT * 144];   // 36KB row buffer
    __shared__ float sred[4][12];

    const int t = threadIdx.x;
    const int tid = blockIdx.x * NT + t;
    const float* cp = cin + (size_t)tid * 36;

    float c[36];
    #pragma unroll
    for (int i = 0; i < 9; ++i)
        *(float4*)(c + 4 * i) = *(const float4*)(cp + 4 * i);

    // retained gt-side scalars for the 5 part losses
    float pd1[5], pbx[5], pgy[5], pvf[5];
    {
        float dx = c[0] - c[28], dy = c[1] - c[29];
        pd1[0] = sqrtf(dx * dx + dy * dy);
        pbx[0] = c[0];
        pgy[0] = c[1] - c[31];
        pvf[0] = (c[0] != -1.f && c[28] != -1.f && c[30] != -1.f) ? 1.f : 0.f;
    }
    #pragma unroll
    for (int p = 0; p < 4; ++p) {
        const int a = 2 + 3 * p, b = a + 1, cc = a + 2;
        float dx = c[2 * a] - c[2 * b], dy = c[2 * a + 1] - c[2 * b + 1];
        pd1[p + 1] = sqrtf(dx * dx + dy * dy);
        pbx[p + 1] = c[2 * b];
        pgy[p + 1] = c[2 * b + 1] - c[2 * cc + 1];
        pvf[p + 1] = (c[2 * a] != -1.f && c[2 * b] != -1.f && c[2 * cc] != -1.f) ? 1.f : 0.f;
    }

    // ---- convs on VALU; weights via uniform (scalar) loads ----
    float a1[10][3];
    #pragma unroll
    for (int o = 0; o < 10; ++o) {
        float acc0 = wf[180 + o], acc1 = acc0;
        #pragma unroll
        for (int i = 0; i < 18; ++i) {
            float w = wf[o * 18 + i];
            acc0 += w * c[2 * i];
            acc1 += w * c[2 * i + 1];
        }
        a1[o][0] = wf[190 + o];
        a1[o][1] = relu_(acc0);
        a1[o][2] = relu_(acc1);
    }
    float a2[20][3];
    #pragma unroll
    for (int o = 0; o < 20; ++o) {
        float bb = wf[600 + o];
        float t0 = bb, t1 = bb, t2 = bb;
        #pragma unroll
        for (int i = 0; i < 10; ++i) {
            float wa = wf[200 + o * 20 + i * 2];
            float wb = wf[200 + o * 20 + i * 2 + 1];
            float p0 = a1[i][0], p1 = a1[i][1], p2 = a1[i][2];
            t0 += p0 * wa + p1 * wb;
            t1 += p1 * wa + p2 * wb;
            t2 += p2 * wa + p0 * wb;   // pos3 == pos0
        }
        a2[o][0] = relu_(t0);
        a2[o][1] = relu_(t1);
        a2[o][2] = relu_(t2);
    }
    // conv3: stream output pairs straight to own LDS row as packed bf16
    #pragma unroll
    for (int o = 0; o < 30; ++o) {
        float bb = wf[1820 + o];
        float t0 = bb, t1 = bb;
        #pragma unroll
        for (int i = 0; i < 20; ++i) {
            float wa = wf[620 + o * 40 + i * 2];
            float wb = wf[620 + o * 40 + i * 2 + 1];
            t0 += a2[i][0] * wa + a2[i][1] * wb;
            t1 += a2[i][1] * wa + a2[i][2] * wb;
        }
        unsigned pk = ((unsigned)(unsigned short)f2bf(relu_(t0))) |
                      (((unsigned)(unsigned short)f2bf(relu_(t1))) << 16);
        *(unsigned*)&sAB[swz((unsigned)t, (unsigned)(o * 4))] = pk;
    }
    // zero cols 60..63 (bytes 120..127)
    *(unsigned*)&sAB[swz((unsigned)t, 120u)] = 0u;
    *(unsigned*)&sAB[swz((unsigned)t, 124u)] = 0u;

    // ---- MFMA FC section (wave-private rows; in-order DS => no barriers) ----
    const int lane = t & 63;
    const unsigned wbase = (unsigned)(t & ~63);
    const unsigned lrow  = (unsigned)(lane & 15);
    const unsigned lkg   = (unsigned)(lane >> 4);   // 0..3

    float fb1v[7], fb2v[3];
    #pragma unroll
    for (int n = 0; n < 7; ++n) { int j = 16 * n + (int)lrow; fb1v[n] = (j < 100) ? fb1[j] : 0.f; }
    #pragma unroll
    for (int n = 0; n < 3; ++n) { int cc = 16 * n + (int)lrow; fb2v[n] = (cc < 36) ? fb2[cc] : 0.f; }

    const short8* f1p = (const short8*)fr1;   // [pos*64+lane]
    const short8* f2p = (const short8*)fr2;

    #pragma unroll 1
    for (int m = 0; m < 4; ++m) {
        const unsigned Rbase = wbase + 16u * (unsigned)m;
        const unsigned myrow = Rbase + lrow;

        short8 A1a = *(const short8*)&sAB[swz(myrow, lkg * 16u)];
        short8 A1b = *(const short8*)&sAB[swz(myrow, 64u + lkg * 16u)];

        f32x4 acc1[7];
        #pragma unroll
        for (int n = 0; n < 7; ++n) acc1[n] = (f32x4){0.f, 0.f, 0.f, 0.f};
        #pragma unroll
        for (int n = 0; n < 7; ++n) {
            short8 b0 = f1p[(n * 2 + 0) * 64 + lane];
            acc1[n] = __builtin_amdgcn_mfma_f32_16x16x32_bf16(A1a, b0, acc1[n], 0, 0, 0);
            short8 b1 = f1p[(n * 2 + 1) * 64 + lane];
            acc1[n] = __builtin_amdgcn_mfma_f32_16x16x32_bf16(A1b, b1, acc1[n], 0, 0, 0);
        }

        f32x4 acc2[3];
        #pragma unroll
        for (int n = 0; n < 3; ++n) acc2[n] = (f32x4){0.f, 0.f, 0.f, 0.f};

        #pragma unroll
        for (int h = 0; h < 2; ++h) {
            // write z cols [64h..64h+63] (bf16) into this tile's 16 rows
            #pragma unroll
            for (int nn = 0; nn < 4; ++nn) {
                const int n = 4 * h + nn;
                #pragma unroll
                for (int i = 0; i < 4; ++i) {
                    float zv = 0.f;
                    if (n < 7) zv = relu_(acc1[n][i] + fb1v[n]);
                    const unsigned row = Rbase + 4u * lkg + (unsigned)i;
                    *(short*)&sAB[swz(row, (unsigned)((16 * nn + (int)lrow) * 2))] = f2bf(zv);
                }
            }
            // consume as fc2 A-frags for kt = 2h, 2h+1
            #pragma unroll
            for (int q = 0; q < 2; ++q) {
                const int kt = 2 * h + q;
                short8 A2 = *(const short8*)&sAB[swz(myrow, (unsigned)(q * 64) + lkg * 16u)];
                #pragma unroll
                for (int n = 0; n < 3; ++n) {
                    short8 b2 = f2p[(n * 4 + kt) * 64 + lane];
                    acc2[n] = __builtin_amdgcn_mfma_f32_16x16x32_bf16(A2, b2, acc2[n], 0, 0, 0);
                }
            }
        }

        // out (f32) -> this tile's rows, cols 0..35
        #pragma unroll
        for (int n = 0; n < 3; ++n) {
            const unsigned col = 16u * (unsigned)n + lrow;
            #pragma unroll
            for (int i = 0; i < 4; ++i) {
                if (col < 36u) {
                    const unsigned row = Rbase + 4u * lkg + (unsigned)i;
                    *(float*)&sAB[swz(row, col * 4u)] = acc2[n][i] + fb2v[n];
                }
            }
        }
    }

    // ---- per-sample part losses from own out-row (cols 0..31) ----
    float o[32];
    #pragma unroll
    for (int b = 0; b < 8; ++b) {
        float4 v = *(const float4*)&sAB[swz((unsigned)t, (unsigned)(b * 16))];
        o[4 * b + 0] = v.x; o[4 * b + 1] = v.y; o[4 * b + 2] = v.z; o[4 * b + 3] = v.w;
    }

    float sp[5], np[5];
    {
        float dxa = o[0] - o[28], dya = o[1] - o[29];
        float dxb = o[0] - o[30], dyb = o[1] - o[31];
        float pred = 0.5f * (sqrtf(dxa*dxa + dya*dya) + sqrtf(dxb*dxb + dyb*dyb));
        float gxa = pbx[0] - o[30];
        float gt = 0.5f * (pd1[0] + sqrtf(gxa * gxa + pgy[0] * pgy[0]));
        float e = pred - gt;
        sp[0] = e * e * pvf[0]; np[0] = pvf[0];
    }
    #pragma unroll
    for (int p = 0; p < 4; ++p) {
        const int a = 2 + 3 * p, b = a + 1, cc = a + 2;
        float dxa = o[2*a] - o[2*b],  dya = o[2*a+1] - o[2*b+1];
        float dxb = o[2*b] - o[2*cc], dyb = o[2*b+1] - o[2*cc+1];
        float pred = 0.5f * (sqrtf(dxa*dxa + dya*dya) + sqrtf(dxb*dxb + dyb*dyb));
        float gxa = pbx[p + 1] - o[2 * cc];
        float gt = 0.5f * (pd1[p + 1] + sqrtf(gxa * gxa + pgy[p + 1] * pgy[p + 1]));
        float e = pred - gt;
        sp[p + 1] = e * e * pvf[p + 1]; np[p + 1] = pvf[p + 1];
    }

    __syncthreads();   // all waves' out-rows complete

    // ---- coalesced x store + miss store + elementwise kp-loss ----
    const size_t blkBase = (size_t)blockIdx.x * (NT * 36);
    const float4* cin4 = (const float4*)(cin + blkBase);
    const int4*   tm4  = (const int4*)(tmask + blkBase);
    float4*       x4   = (float4*)(xout + blkBase);
    float*        mo   = missout + blkBase;

    float s1 = 0.f, s2 = 0.f;
    #pragma unroll
    for (int i = 0; i < 9; ++i) {
        int g4 = i * NT + t;
        unsigned g = 4u * (unsigned)g4;
        unsigned row = g / 36u;
        unsigned col = g - row * 36u;          // %4 == 0 -> one 16B block
        float4 xv = *(const float4*)&sAB[swz(row, col * 4u)];
        float4 cv = cin4[g4];
        int4   mv = tm4[g4];
        x4[g4] = xv;
        mo[g + 0] = (cv.x != -1.f) ? 1.f : 0.f;
        mo[g + 1] = (cv.y != -1.f) ? 1.f : 0.f;
        mo[g + 2] = (cv.z != -1.f) ? 1.f : 0.f;
        mo[g + 3] = (cv.w != -1.f) ? 1.f : 0.f;
        float m0 = (float)mv.x, m1_ = (float)mv.y, m2_ = (float)mv.z, m3_ = (float)mv.w;
        float d0 = xv.x - cv.x, d1 = xv.y - cv.y, d2 = xv.z - cv.z, d3 = xv.w - cv.w;
        s1 += d0*d0*m0 + d1*d1*m1_ + d2*d2*m2_ + d3*d3*m3_;
        s2 += m0 + m1_ + m2_ + m3_;
    }

    // ---- block reduction of 12 scalars ----
    float rv[12] = { s1, s2, sp[0], np[0], sp[1], np[1],
                     sp[2], np[2], sp[3], np[3], sp[4], np[4] };
    #pragma unroll
    for (int v = 0; v < 12; ++v) {
        #pragma unroll
        for (int off = 32; off > 0; off >>= 1)
            rv[v] += __shfl_down(rv[v], off, 64);
    }
    const int wave = t >> 6, lane6 = t & 63;
    if (lane6 == 0) {
        #pragma unroll
        for (int v = 0; v < 12; ++v) sred[wave][v] = rv[v];
    }
    __syncthreads();
    if (t < 12) {
        float s = sred[0][t] + sred[1][t] + sred[2][t] + sred[3][t];
        partials[blockIdx.x * 12 + t] = s;
    }
}

__global__ __launch_bounds__(256) void kp_fin(const float* __restrict__ partials,
                                              float* __restrict__ total_out)
{
    __shared__ float sred[4][12];
    const int t = threadIdx.x;
    float rv[12];
    #pragma unroll
    for (int v = 0; v < 12; ++v) rv[v] = 0.f;
    for (int b = t; b < NB; b += 256) {
        #pragma unroll
        for (int v = 0; v < 12; ++v) rv[v] += partials[b * 12 + v];
    }
    #pragma unroll
    for (int v = 0; v < 12; ++v) {
        #pragma unroll
        for (int off = 32; off > 0; off >>= 1)
            rv[v] += __shfl_down(rv[v], off, 64);
    }
    const int wave = t >> 6, lane = t & 63;
    if (lane == 0) {
        #pragma unroll
        for (int v = 0; v < 12; ++v) sred[wave][v] = rv[v];
    }
    __syncthreads();
    if (t == 0) {
        float acc[12];
        #pragma unroll
        for (int v = 0; v < 12; ++v)
            acc[v] = sred[0][v] + sred[1][v] + sred[2][v] + sred[3][v];
        float total = acc[0] / acc[1];
        #pragma unroll
        for (int p = 0; p < 5; ++p) {
            float s = acc[2 + 2 * p], n = acc[3 + 2 * p];
            total += (n > 0.f) ? (s / fmaxf(n, 1.f)) : 0.f;
        }
        total_out[0] = total;
    }
}

extern "C" void kernel_launch(void* const* d_in, const int* in_sizes, int n_in,
                              void* d_out, int out_size, void* d_ws, size_t ws_size,
                              hipStream_t stream)
{
    const float* cin   = (const float*)d_in[0];
    const int*   tmask = (const int*)  d_in[1];
    const float* w1  = (const float*)d_in[2];
    const float* b1  = (const float*)d_in[3];
    const float* g1  = (const float*)d_in[4];
    const float* bt1 = (const float*)d_in[5];
    const float* m1  = (const float*)d_in[6];
    const float* v1  = (const float*)d_in[7];
    const float* w2  = (const float*)d_in[8];
    const float* b2  = (const float*)d_in[9];
    const float* g2  = (const float*)d_in[10];
    const float* bt2 = (const float*)d_in[11];
    const float* m2  = (const float*)d_in[12];
    const float* v2  = (const float*)d_in[13];
    const float* w3  = (const float*)d_in[14];
    const float* b3  = (const float*)d_in[15];
    const float* g3  = (const float*)d_in[16];
    const float* bt3 = (const float*)d_in[17];
    const float* m3  = (const float*)d_in[18];
    const float* v3  = (const float*)d_in[19];
    const float* fw1 = (const float*)d_in[20];
    const float* fb1 = (const float*)d_in[21];
    const float* fw2 = (const float*)d_in[22];
    const float* fb2 = (const float*)d_in[23];

    float* xout     = (float*)d_out;                       // [B,36]
    float* total    = (float*)d_out + (size_t)BTOT * 36;   // scalar
    float* missout  = total + 1;                           // [B,36] as f32 0/1

    float* wsf      = (float*)d_ws;
    short* fr1      = (short*)((char*)d_ws + FR1_BYTE);
    short* fr2      = (short*)((char*)d_ws + FR2_BYTE);
    float* partials = (float*)((char*)d_ws + PART_BYTE);   // [NB,12]

    kp_setup<<<1, 256, 0, stream>>>(
        w1, b1, g1, bt1, m1, v1,
        w2, b2, g2, bt2, m2, v2,
        w3, b3, g3, bt3, m3, v3,
        fw1, fw2, wsf, fr1, fr2);

    kp_fwd<<<NB, NT, 0, stream>>>(cin, tmask, wsf, fr1, fr2,
        fb1, fb2, xout, missout, partials);

    kp_fin<<<1, 256, 0, stream>>>(partials, total);
}

// Round 5
// 134.192 us; speedup vs baseline: 1.1911x; 1.1911x over previous
//
#include <hip/hip_runtime.h>

#define NB   1024
#define NT   256
#define BTOT 262144   // NB*NT == B

typedef __attribute__((ext_vector_type(8))) short short8;
typedef __attribute__((ext_vector_type(4))) float f32x4;

__device__ __forceinline__ float relu_(float x) { return fmaxf(x, 0.0f); }

__device__ __forceinline__ short f2bf(float x) {   // RNE f32->bf16
    unsigned u = __float_as_uint(x);
    unsigned r = (u + 0x7FFFu + ((u >> 16) & 1u)) >> 16;
    return (short)r;
}

// 144B rows; XOR-swizzle the 16B-block index with row&7 (blocks 0..7;
// block 8 = bytes 128..143 stays linear).
__device__ __forceinline__ unsigned swz(unsigned row, unsigned byteoff) {
    unsigned blk = byteoff >> 4, rest = byteoff & 15u;
    if (blk < 8u) blk ^= (row & 7u);
    return row * 144u + blk * 16u + rest;
}

// d_ws float-offset layout:
//   W1 0..179 | B1 180..189 | A0 190..199 | W2 200..599 | B2 600..619
//   W3 620..1819 | B3 1820..1849
// byte 7424:  fc1 frags (14*512 shorts)
// byte 21760: fc2 frags (12*512 shorts)
// byte 34048: partials [NB*12] f32
#define FR1_BYTE 7424
#define FR2_BYTE 21760
#define PART_BYTE 34048

__global__ __launch_bounds__(256) void kp_setup(
    const float* __restrict__ w1, const float* __restrict__ b1,
    const float* __restrict__ g1, const float* __restrict__ bt1,
    const float* __restrict__ m1, const float* __restrict__ v1,
    const float* __restrict__ w2, const float* __restrict__ b2,
    const float* __restrict__ g2, const float* __restrict__ bt2,
    const float* __restrict__ m2, const float* __restrict__ v2,
    const float* __restrict__ w3, const float* __restrict__ b3,
    const float* __restrict__ g3, const float* __restrict__ bt3,
    const float* __restrict__ m3, const float* __restrict__ v3,
    const float* __restrict__ fw1, const float* __restrict__ fw2,
    float* __restrict__ wsf, short* __restrict__ fr1, short* __restrict__ fr2)
{
    const int t = threadIdx.x;
    if (t < 10) {
        float s  = g1[t] * rsqrtf(v1[t] + 1e-5f);
        float bb = (b1[t] - m1[t]) * s + bt1[t];
        wsf[180 + t] = bb;
        wsf[190 + t] = relu_(bb);
        for (int i = 0; i < 18; ++i) wsf[t * 18 + i] = w1[t * 18 + i] * s;
    } else if (t >= 64 && t < 84) {
        int o = t - 64;
        float s = g2[o] * rsqrtf(v2[o] + 1e-5f);
        wsf[600 + o] = (b2[o] - m2[o]) * s + bt2[o];
        for (int i = 0; i < 20; ++i) wsf[200 + o * 20 + i] = w2[o * 20 + i] * s;
    } else if (t >= 128 && t < 158) {
        int o = t - 128;
        float s = g3[o] * rsqrtf(v3[o] + 1e-5f);
        wsf[1820 + o] = (b3[o] - m3[o]) * s + bt3[o];
        for (int i = 0; i < 40; ++i) wsf[620 + o * 40 + i] = w3[o * 40 + i] * s;
    }
    // fc1 B-frags: B1[k][j] = fw1[j*60+k]
    for (int e = t; e < 14 * 512; e += 256) {
        int pos = e >> 9, l = (e >> 3) & 63, j = e & 7;
        int n = pos >> 1, kt = pos & 1;
        int col = 16 * n + (l & 15);
        int k   = kt * 32 + (l >> 4) * 8 + j;
        float v = (col < 100 && k < 60) ? fw1[col * 60 + k] : 0.f;
        fr1[e] = f2bf(v);
    }
    // fc2 B-frags: B2[k][cc] = fw2[cc*100+k]
    for (int e = t; e < 12 * 512; e += 256) {
        int pos = e >> 9, l = (e >> 3) & 63, j = e & 7;
        int n = pos >> 2, kt = pos & 3;
        int col = 16 * n + (l & 15);
        int k   = kt * 32 + (l >> 4) * 8 + j;
        float v = (col < 36 && k < 100) ? fw2[col * 100 + k] : 0.f;
        fr2[e] = f2bf(v);
    }
}

__global__ __launch_bounds__(NT) void kp_fwd(
    const float* __restrict__ cin, const int* __restrict__ tmask,
    const float* __restrict__ wf,          // folded weights (uniform -> s_load)
    const short* __restrict__ fr1,         // fc1 B-frags
    const short* __restrict__ fr2,         // fc2 B-frags
    const float* __restrict__ fb1, const float* __restrict__ fb2,
    float* __restrict__ xout, float* __restrict__ missout,
    float* __restrict__ partials)
{
    __shared__ __align__(16) unsigned char sAB[NT * 144];   // 36KB row buffer
    __shared__ float sred[4][12];

    const int t = threadIdx.x;
    const int tid = blockIdx.x * NT + t;
    const float* cp = cin + (size_t)tid * 36;

    float c[36];
    #pragma unroll
    for (int i = 0; i < 9; ++i)
        *(float4*)(c + 4 * i) = *(const float4*)(cp + 4 * i);

    // retained gt-side scalars for the 5 part losses
    float pd1[5], pbx[5], pgy[5], pvf[5];
    {
        float dx = c[0] - c[28], dy = c[1] - c[29];
        pd1[0] = sqrtf(dx * dx + dy * dy);
        pbx[0] = c[0];
        pgy[0] = c[1] - c[31];
        pvf[0] = (c[0] != -1.f && c[28] != -1.f && c[30] != -1.f) ? 1.f : 0.f;
    }
    #pragma unroll
    for (int p = 0; p < 4; ++p) {
        const int a = 2 + 3 * p, b = a + 1, cc = a + 2;
        float dx = c[2 * a] - c[2 * b], dy = c[2 * a + 1] - c[2 * b + 1];
        pd1[p + 1] = sqrtf(dx * dx + dy * dy);
        pbx[p + 1] = c[2 * b];
        pgy[p + 1] = c[2 * b + 1] - c[2 * cc + 1];
        pvf[p + 1] = (c[2 * a] != -1.f && c[2 * b] != -1.f && c[2 * cc] != -1.f) ? 1.f : 0.f;
    }

    // ---- convs on VALU; weights via uniform (scalar) loads ----
    float a1[10][3];
    #pragma unroll
    for (int o = 0; o < 10; ++o) {
        float acc0 = wf[180 + o], acc1 = acc0;
        #pragma unroll
        for (int i = 0; i < 18; ++i) {
            float w = wf[o * 18 + i];
            acc0 += w * c[2 * i];
            acc1 += w * c[2 * i + 1];
        }
        a1[o][0] = wf[190 + o];
        a1[o][1] = relu_(acc0);
        a1[o][2] = relu_(acc1);
    }
    float a2[20][3];
    #pragma unroll
    for (int o = 0; o < 20; ++o) {
        float bb = wf[600 + o];
        float t0 = bb, t1 = bb, t2 = bb;
        #pragma unroll
        for (int i = 0; i < 10; ++i) {
            float wa = wf[200 + o * 20 + i * 2];
            float wb = wf[200 + o * 20 + i * 2 + 1];
            float p0 = a1[i][0], p1 = a1[i][1], p2 = a1[i][2];
            t0 += p0 * wa + p1 * wb;
            t1 += p1 * wa + p2 * wb;
            t2 += p2 * wa + p0 * wb;   // pos3 == pos0
        }
        a2[o][0] = relu_(t0);
        a2[o][1] = relu_(t1);
        a2[o][2] = relu_(t2);
    }
    // conv3: pack outputs as bf16 pairs in registers, then 8 x b128 to LDS
    unsigned fpk[32];
    #pragma unroll
    for (int o = 0; o < 30; ++o) {
        float bb = wf[1820 + o];
        float t0 = bb, t1 = bb;
        #pragma unroll
        for (int i = 0; i < 20; ++i) {
            float wa = wf[620 + o * 40 + i * 2];
            float wb = wf[620 + o * 40 + i * 2 + 1];
            t0 += a2[i][0] * wa + a2[i][1] * wb;
            t1 += a2[i][1] * wa + a2[i][2] * wb;
        }
        fpk[o] = ((unsigned)(unsigned short)f2bf(relu_(t0))) |
                 (((unsigned)(unsigned short)f2bf(relu_(t1))) << 16);
    }
    fpk[30] = 0u; fpk[31] = 0u;   // cols 60..63
    #pragma unroll
    for (int b = 0; b < 8; ++b)
        *(uint4*)&sAB[swz((unsigned)t, (unsigned)(b * 16))] = *(const uint4*)&fpk[b * 4];

    // ---- MFMA FC section (wave-private rows; in-order DS => no barriers) ----
    const int lane = t & 63;
    const unsigned wbase = (unsigned)(t & ~63);
    const unsigned lrow  = (unsigned)(lane & 15);
    const unsigned lkg   = (unsigned)(lane >> 4);   // 0..3

    float fb1v[7], fb2v[3];
    #pragma unroll
    for (int n = 0; n < 7; ++n) { int j = 16 * n + (int)lrow; fb1v[n] = (j < 100) ? fb1[j] : 0.f; }
    #pragma unroll
    for (int n = 0; n < 3; ++n) { int cc = 16 * n + (int)lrow; fb2v[n] = (cc < 36) ? fb2[cc] : 0.f; }

    const short8* f1p = (const short8*)fr1;   // [pos*64+lane]
    const short8* f2p = (const short8*)fr2;

    #pragma unroll 1
    for (int m = 0; m < 4; ++m) {
        const unsigned Rbase = wbase + 16u * (unsigned)m;
        const unsigned myrow = Rbase + lrow;

        short8 A1a = *(const short8*)&sAB[swz(myrow, lkg * 16u)];
        short8 A1b = *(const short8*)&sAB[swz(myrow, 64u + lkg * 16u)];

        f32x4 acc1[7];
        #pragma unroll
        for (int n = 0; n < 7; ++n) acc1[n] = (f32x4){0.f, 0.f, 0.f, 0.f};
        #pragma unroll
        for (int n = 0; n < 7; ++n) {
            short8 b0 = f1p[(n * 2 + 0) * 64 + lane];
            acc1[n] = __builtin_amdgcn_mfma_f32_16x16x32_bf16(A1a, b0, acc1[n], 0, 0, 0);
            short8 b1 = f1p[(n * 2 + 1) * 64 + lane];
            acc1[n] = __builtin_amdgcn_mfma_f32_16x16x32_bf16(A1b, b1, acc1[n], 0, 0, 0);
        }

        f32x4 acc2[3];
        #pragma unroll
        for (int n = 0; n < 3; ++n) acc2[n] = (f32x4){0.f, 0.f, 0.f, 0.f};

        #pragma unroll
        for (int h = 0; h < 2; ++h) {
            // write z cols [64h..64h+63] (bf16) into this tile's 16 rows
            #pragma unroll
            for (int nn = 0; nn < 4; ++nn) {
                const int n = 4 * h + nn;
                #pragma unroll
                for (int i = 0; i < 4; ++i) {
                    float zv = 0.f;
                    if (n < 7) zv = relu_(acc1[n][i] + fb1v[n]);
                    const unsigned row = Rbase + 4u * lkg + (unsigned)i;
                    *(short*)&sAB[swz(row, (unsigned)((16 * nn + (int)lrow) * 2))] = f2bf(zv);
                }
            }
            // consume as fc2 A-frags for kt = 2h, 2h+1
            #pragma unroll
            for (int q = 0; q < 2; ++q) {
                const int kt = 2 * h + q;
                short8 A2 = *(const short8*)&sAB[swz(myrow, (unsigned)(q * 64) + lkg * 16u)];
                #pragma unroll
                for (int n = 0; n < 3; ++n) {
                    short8 b2 = f2p[(n * 4 + kt) * 64 + lane];
                    acc2[n] = __builtin_amdgcn_mfma_f32_16x16x32_bf16(A2, b2, acc2[n], 0, 0, 0);
                }
            }
        }

        // out (f32) -> this tile's rows, cols 0..35
        #pragma unroll
        for (int n = 0; n < 3; ++n) {
            const unsigned col = 16u * (unsigned)n + lrow;
            #pragma unroll
            for (int i = 0; i < 4; ++i) {
                if (col < 36u) {
                    const unsigned row = Rbase + 4u * lkg + (unsigned)i;
                    *(float*)&sAB[swz(row, col * 4u)] = acc2[n][i] + fb2v[n];
                }
            }
        }
    }

    // ---- per-sample part losses from own out-row (cols 0..31) ----
    float o[32];
    #pragma unroll
    for (int b = 0; b < 8; ++b) {
        float4 v = *(const float4*)&sAB[swz((unsigned)t, (unsigned)(b * 16))];
        o[4 * b + 0] = v.x; o[4 * b + 1] = v.y; o[4 * b + 2] = v.z; o[4 * b + 3] = v.w;
    }

    float sp[5], np[5];
    {
        float dxa = o[0] - o[28], dya = o[1] - o[29];
        float dxb = o[0] - o[30], dyb = o[1] - o[31];
        float pred = 0.5f * (sqrtf(dxa*dxa + dya*dya) + sqrtf(dxb*dxb + dyb*dyb));
        float gxa = pbx[0] - o[30];
        float gt = 0.5f * (pd1[0] + sqrtf(gxa * gxa + pgy[0] * pgy[0]));
        float e = pred - gt;
        sp[0] = e * e * pvf[0]; np[0] = pvf[0];
    }
    #pragma unroll
    for (int p = 0; p < 4; ++p) {
        const int a = 2 + 3 * p, b = a + 1, cc = a + 2;
        float dxa = o[2*a] - o[2*b],  dya = o[2*a+1] - o[2*b+1];
        float dxb = o[2*b] - o[2*cc], dyb = o[2*b+1] - o[2*cc+1];
        float pred = 0.5f * (sqrtf(dxa*dxa + dya*dya) + sqrtf(dxb*dxb + dyb*dyb));
        float gxa = pbx[p + 1] - o[2 * cc];
        float gt = 0.5f * (pd1[p + 1] + sqrtf(gxa * gxa + pgy[p + 1] * pgy[p + 1]));
        float e = pred - gt;
        sp[p + 1] = e * e * pvf[p + 1]; np[p + 1] = pvf[p + 1];
    }

    __syncthreads();   // all waves' out-rows complete

    // ---- coalesced x store + miss store + elementwise kp-loss ----
    const size_t blkBase = (size_t)blockIdx.x * (NT * 36);
    const float4* cin4 = (const float4*)(cin + blkBase);
    const int4*   tm4  = (const int4*)(tmask + blkBase);
    float4*       x4   = (float4*)(xout + blkBase);
    float*        mo   = missout + blkBase;

    float s1 = 0.f, s2 = 0.f;
    #pragma unroll
    for (int i = 0; i < 9; ++i) {
        int g4 = i * NT + t;
        unsigned g = 4u * (unsigned)g4;
        unsigned row = g / 36u;
        unsigned col = g - row * 36u;          // %4 == 0 -> one 16B block
        float4 xv = *(const float4*)&sAB[swz(row, col * 4u)];
        float4 cv = cin4[g4];
        int4   mv = tm4[g4];
        x4[g4] = xv;
        mo[g + 0] = (cv.x != -1.f) ? 1.f : 0.f;
        mo[g + 1] = (cv.y != -1.f) ? 1.f : 0.f;
        mo[g + 2] = (cv.z != -1.f) ? 1.f : 0.f;
        mo[g + 3] = (cv.w != -1.f) ? 1.f : 0.f;
        float m0 = (float)mv.x, m1_ = (float)mv.y, m2_ = (float)mv.z, m3_ = (float)mv.w;
        float d0 = xv.x - cv.x, d1 = xv.y - cv.y, d2 = xv.z - cv.z, d3 = xv.w - cv.w;
        s1 += d0*d0*m0 + d1*d1*m1_ + d2*d2*m2_ + d3*d3*m3_;
        s2 += m0 + m1_ + m2_ + m3_;
    }

    // ---- block reduction of 12 scalars ----
    float rv[12] = { s1, s2, sp[0], np[0], sp[1], np[1],
                     sp[2], np[2], sp[3], np[3], sp[4], np[4] };
    #pragma unroll
    for (int v = 0; v < 12; ++v) {
        #pragma unroll
        for (int off = 32; off > 0; off >>= 1)
            rv[v] += __shfl_down(rv[v], off, 64);
    }
    const int wave = t >> 6, lane6 = t & 63;
    if (lane6 == 0) {
        #pragma unroll
        for (int v = 0; v < 12; ++v) sred[wave][v] = rv[v];
    }
    __syncthreads();
    if (t < 12) {
        float s = sred[0][t] + sred[1][t] + sred[2][t] + sred[3][t];
        partials[blockIdx.x * 12 + t] = s;
    }
}

__global__ __launch_bounds__(256) void kp_fin(const float* __restrict__ partials,
                                              float* __restrict__ total_out)
{
    __shared__ float sred[4][12];
    const int t = threadIdx.x;
    float rv[12];
    #pragma unroll
    for (int v = 0; v < 12; ++v) rv[v] = 0.f;
    for (int b = t; b < NB; b += 256) {
        #pragma unroll
        for (int v = 0; v < 12; ++v) rv[v] += partials[b * 12 + v];
    }
    #pragma unroll
    for (int v = 0; v < 12; ++v) {
        #pragma unroll
        for (int off = 32; off > 0; off >>= 1)
            rv[v] += __shfl_down(rv[v], off, 64);
    }
    const int wave = t >> 6, lane = t & 63;
    if (lane == 0) {
        #pragma unroll
        for (int v = 0; v < 12; ++v) sred[wave][v] = rv[v];
    }
    __syncthreads();
    if (t == 0) {
        float acc[12];
        #pragma unroll
        for (int v = 0; v < 12; ++v)
            acc[v] = sred[0][v] + sred[1][v] + sred[2][v] + sred[3][v];
        float total = acc[0] / acc[1];
        #pragma unroll
        for (int p = 0; p < 5; ++p) {
            float s = acc[2 + 2 * p], n = acc[3 + 2 * p];
            total += (n > 0.f) ? (s / fmaxf(n, 1.f)) : 0.f;
        }
        total_out[0] = total;
    }
}

extern "C" void kernel_launch(void* const* d_in, const int* in_sizes, int n_in,
                              void* d_out, int out_size, void* d_ws, size_t ws_size,
                              hipStream_t stream)
{
    const float* cin   = (const float*)d_in[0];
    const int*   tmask = (const int*)  d_in[1];
    const float* w1  = (const float*)d_in[2];
    const float* b1  = (const float*)d_in[3];
    const float* g1  = (const float*)d_in[4];
    const float* bt1 = (const float*)d_in[5];
    const float* m1  = (const float*)d_in[6];
    const float* v1  = (const float*)d_in[7];
    const float* w2  = (const float*)d_in[8];
    const float* b2  = (const float*)d_in[9];
    const float* g2  = (const float*)d_in[10];
    const float* bt2 = (const float*)d_in[11];
    const float* m2  = (const float*)d_in[12];
    const float* v2  = (const float*)d_in[13];
    const float* w3  = (const float*)d_in[14];
    const float* b3  = (const float*)d_in[15];
    const float* g3  = (const float*)d_in[16];
    const float* bt3 = (const float*)d_in[17];
    const float* m3  = (const float*)d_in[18];
    const float* v3  = (const float*)d_in[19];
    const float* fw1 = (const float*)d_in[20];
    const float* fb1 = (const float*)d_in[21];
    const float* fw2 = (const float*)d_in[22];
    const float* fb2 = (const float*)d_in[23];

    float* xout     = (float*)d_out;                       // [B,36]
    float* total    = (float*)d_out + (size_t)BTOT * 36;   // scalar
    float* missout  = total + 1;                           // [B,36] as f32 0/1

    float* wsf      = (float*)d_ws;
    short* fr1      = (short*)((char*)d_ws + FR1_BYTE);
    short* fr2      = (short*)((char*)d_ws + FR2_BYTE);
    float* partials = (float*)((char*)d_ws + PART_BYTE);   // [NB,12]

    kp_setup<<<1, 256, 0, stream>>>(
        w1, b1, g1, bt1, m1, v1,
        w2, b2, g2, bt2, m2, v2,
        w3, b3, g3, bt3, m3, v3,
        fw1, fw2, wsf, fr1, fr2);

    kp_fwd<<<NB, NT, 0, stream>>>(cin, tmask, wsf, fr1, fr2,
        fb1, fb2, xout, missout, partials);

    kp_fin<<<1, 256, 0, stream>>>(partials, total);
}

// Round 6
// 128.496 us; speedup vs baseline: 1.2439x; 1.0443x over previous
//
#include <hip/hip_runtime.h>

#define NB   1024
#define NT   256
#define BTOT 262144   // NB*NT == B

typedef __attribute__((ext_vector_type(8))) short short8;
typedef __attribute__((ext_vector_type(4))) float f32x4;

__device__ __forceinline__ float relu_(float x) { return fmaxf(x, 0.0f); }

__device__ __forceinline__ short f2bf(float x) {   // RNE f32->bf16
    unsigned u = __float_as_uint(x);
    unsigned r = (u + 0x7FFFu + ((u >> 16) & 1u)) >> 16;
    return (short)r;
}

// 144B rows, LINEAR. 144 B = 36 dwords = 4 mod 32 banks: consecutive rows are
// naturally staggered by one 16B block, so column reads (A-frags: 16 rows,
// same block) spread across banks WITHOUT an explicit swizzle. (The r4/r5
// XOR swizzle cancelled this stagger -> 4-way conflicts; removed.)
__device__ __forceinline__ unsigned lidx(unsigned row, unsigned byteoff) {
    return row * 144u + byteoff;
}

// d_ws float-offset layout:
//   W1 0..179 | B1 180..189 | A0 190..199 | W2 200..599 | B2 600..619
//   W3 620..1819 | B3 1820..1849
// byte 7424:  fc1 frags (14*512 shorts)
// byte 21760: fc2 frags (12*512 shorts)
// byte 34048: partials [NB*12] f32
#define FR1_BYTE 7424
#define FR2_BYTE 21760
#define PART_BYTE 34048

__global__ __launch_bounds__(256) void kp_setup(
    const float* __restrict__ w1, const float* __restrict__ b1,
    const float* __restrict__ g1, const float* __restrict__ bt1,
    const float* __restrict__ m1, const float* __restrict__ v1,
    const float* __restrict__ w2, const float* __restrict__ b2,
    const float* __restrict__ g2, const float* __restrict__ bt2,
    const float* __restrict__ m2, const float* __restrict__ v2,
    const float* __restrict__ w3, const float* __restrict__ b3,
    const float* __restrict__ g3, const float* __restrict__ bt3,
    const float* __restrict__ m3, const float* __restrict__ v3,
    const float* __restrict__ fw1, const float* __restrict__ fw2,
    float* __restrict__ wsf, short* __restrict__ fr1, short* __restrict__ fr2)
{
    const int t = threadIdx.x;
    if (t < 10) {
        float s  = g1[t] * rsqrtf(v1[t] + 1e-5f);
        float bb = (b1[t] - m1[t]) * s + bt1[t];
        wsf[180 + t] = bb;
        wsf[190 + t] = relu_(bb);
        for (int i = 0; i < 18; ++i) wsf[t * 18 + i] = w1[t * 18 + i] * s;
    } else if (t >= 64 && t < 84) {
        int o = t - 64;
        float s = g2[o] * rsqrtf(v2[o] + 1e-5f);
        wsf[600 + o] = (b2[o] - m2[o]) * s + bt2[o];
        for (int i = 0; i < 20; ++i) wsf[200 + o * 20 + i] = w2[o * 20 + i] * s;
    } else if (t >= 128 && t < 158) {
        int o = t - 128;
        float s = g3[o] * rsqrtf(v3[o] + 1e-5f);
        wsf[1820 + o] = (b3[o] - m3[o]) * s + bt3[o];
        for (int i = 0; i < 40; ++i) wsf[620 + o * 40 + i] = w3[o * 40 + i] * s;
    }
    // fc1 B-frags: B1[k][j] = fw1[j*60+k]
    for (int e = t; e < 14 * 512; e += 256) {
        int pos = e >> 9, l = (e >> 3) & 63, j = e & 7;
        int n = pos >> 1, kt = pos & 1;
        int col = 16 * n + (l & 15);
        int k   = kt * 32 + (l >> 4) * 8 + j;
        float v = (col < 100 && k < 60) ? fw1[col * 60 + k] : 0.f;
        fr1[e] = f2bf(v);
    }
    // fc2 B-frags: B2[k][cc] = fw2[cc*100+k]
    for (int e = t; e < 12 * 512; e += 256) {
        int pos = e >> 9, l = (e >> 3) & 63, j = e & 7;
        int n = pos >> 2, kt = pos & 3;
        int col = 16 * n + (l & 15);
        int k   = kt * 32 + (l >> 4) * 8 + j;
        float v = (col < 36 && k < 100) ? fw2[col * 100 + k] : 0.f;
        fr2[e] = f2bf(v);
    }
}

__global__ __launch_bounds__(NT) void kp_fwd(
    const float* __restrict__ cin, const int* __restrict__ tmask,
    const float* __restrict__ wf,          // folded weights (uniform -> s_load)
    const short* __restrict__ fr1,         // fc1 B-frags
    const short* __restrict__ fr2,         // fc2 B-frags
    const float* __restrict__ fb1, const float* __restrict__ fb2,
    float* __restrict__ xout, float* __restrict__ missout,
    float* __restrict__ partials)
{
    __shared__ __align__(16) unsigned char sAB[NT * 144];   // 36KB row buffer
    __shared__ float sred[4][12];

    const int t = threadIdx.x;
    const int tid = blockIdx.x * NT + t;
    const float* cp = cin + (size_t)tid * 36;

    float c[36];
    #pragma unroll
    for (int i = 0; i < 9; ++i)
        *(float4*)(c + 4 * i) = *(const float4*)(cp + 4 * i);

    // retained gt-side scalars for the 5 part losses
    float pd1[5], pbx[5], pgy[5], pvf[5];
    {
        float dx = c[0] - c[28], dy = c[1] - c[29];
        pd1[0] = sqrtf(dx * dx + dy * dy);
        pbx[0] = c[0];
        pgy[0] = c[1] - c[31];
        pvf[0] = (c[0] != -1.f && c[28] != -1.f && c[30] != -1.f) ? 1.f : 0.f;
    }
    #pragma unroll
    for (int p = 0; p < 4; ++p) {
        const int a = 2 + 3 * p, b = a + 1, cc = a + 2;
        float dx = c[2 * a] - c[2 * b], dy = c[2 * a + 1] - c[2 * b + 1];
        pd1[p + 1] = sqrtf(dx * dx + dy * dy);
        pbx[p + 1] = c[2 * b];
        pgy[p + 1] = c[2 * b + 1] - c[2 * cc + 1];
        pvf[p + 1] = (c[2 * a] != -1.f && c[2 * b] != -1.f && c[2 * cc] != -1.f) ? 1.f : 0.f;
    }

    // ---- convs on VALU; weights via uniform (scalar) loads ----
    float a1[10][3];
    #pragma unroll
    for (int o = 0; o < 10; ++o) {
        float acc0 = wf[180 + o], acc1 = acc0;
        #pragma unroll
        for (int i = 0; i < 18; ++i) {
            float w = wf[o * 18 + i];
            acc0 += w * c[2 * i];
            acc1 += w * c[2 * i + 1];
        }
        a1[o][0] = wf[190 + o];
        a1[o][1] = relu_(acc0);
        a1[o][2] = relu_(acc1);
    }
    float a2[20][3];
    #pragma unroll
    for (int o = 0; o < 20; ++o) {
        float bb = wf[600 + o];
        float t0 = bb, t1 = bb, t2 = bb;
        #pragma unroll
        for (int i = 0; i < 10; ++i) {
            float wa = wf[200 + o * 20 + i * 2];
            float wb = wf[200 + o * 20 + i * 2 + 1];
            float p0 = a1[i][0], p1 = a1[i][1], p2 = a1[i][2];
            t0 += p0 * wa + p1 * wb;
            t1 += p1 * wa + p2 * wb;
            t2 += p2 * wa + p0 * wb;   // pos3 == pos0
        }
        a2[o][0] = relu_(t0);
        a2[o][1] = relu_(t1);
        a2[o][2] = relu_(t2);
    }
    // conv3: rolled over o (small I-footprint, no staging array); one packed
    // bf16-pair dword straight to own LDS row per output channel.
    #pragma unroll 1
    for (int o = 0; o < 30; ++o) {
        float bb = wf[1820 + o];
        float t0 = bb, t1 = bb;
        #pragma unroll
        for (int i = 0; i < 20; ++i) {
            float wa = wf[620 + o * 40 + i * 2];
            float wb = wf[620 + o * 40 + i * 2 + 1];
            t0 += a2[i][0] * wa + a2[i][1] * wb;
            t1 += a2[i][1] * wa + a2[i][2] * wb;
        }
        unsigned pk = ((unsigned)(unsigned short)f2bf(relu_(t0))) |
                      (((unsigned)(unsigned short)f2bf(relu_(t1))) << 16);
        *(unsigned*)&sAB[lidx((unsigned)t, (unsigned)(o * 4))] = pk;
    }
    // zero cols 60..63 (bytes 120..127)
    *(unsigned*)&sAB[lidx((unsigned)t, 120u)] = 0u;
    *(unsigned*)&sAB[lidx((unsigned)t, 124u)] = 0u;

    // ---- MFMA FC section (wave-private rows; in-order DS => no barriers) ----
    const int lane = t & 63;
    const unsigned wbase = (unsigned)(t & ~63);
    const unsigned lrow  = (unsigned)(lane & 15);
    const unsigned lkg   = (unsigned)(lane >> 4);   // 0..3

    float fb1v[7], fb2v[3];
    #pragma unroll
    for (int n = 0; n < 7; ++n) { int j = 16 * n + (int)lrow; fb1v[n] = (j < 100) ? fb1[j] : 0.f; }
    #pragma unroll
    for (int n = 0; n < 3; ++n) { int cc = 16 * n + (int)lrow; fb2v[n] = (cc < 36) ? fb2[cc] : 0.f; }

    const short8* f1p = (const short8*)fr1;   // [pos*64+lane]
    const short8* f2p = (const short8*)fr2;

    #pragma unroll 1
    for (int m = 0; m < 4; ++m) {
        const unsigned Rbase = wbase + 16u * (unsigned)m;
        const unsigned myrow = Rbase + lrow;

        short8 A1a = *(const short8*)&sAB[lidx(myrow, lkg * 16u)];
        short8 A1b = *(const short8*)&sAB[lidx(myrow, 64u + lkg * 16u)];

        f32x4 acc1[7];
        #pragma unroll
        for (int n = 0; n < 7; ++n) acc1[n] = (f32x4){0.f, 0.f, 0.f, 0.f};
        #pragma unroll
        for (int n = 0; n < 7; ++n) {
            short8 b0 = f1p[(n * 2 + 0) * 64 + lane];
            acc1[n] = __builtin_amdgcn_mfma_f32_16x16x32_bf16(A1a, b0, acc1[n], 0, 0, 0);
            short8 b1 = f1p[(n * 2 + 1) * 64 + lane];
            acc1[n] = __builtin_amdgcn_mfma_f32_16x16x32_bf16(A1b, b1, acc1[n], 0, 0, 0);
        }

        f32x4 acc2[3];
        #pragma unroll
        for (int n = 0; n < 3; ++n) acc2[n] = (f32x4){0.f, 0.f, 0.f, 0.f};

        #pragma unroll
        for (int h = 0; h < 2; ++h) {
            // write z cols [64h..64h+63] (bf16) into this tile's 16 rows
            #pragma unroll
            for (int nn = 0; nn < 4; ++nn) {
                const int n = 4 * h + nn;
                #pragma unroll
                for (int i = 0; i < 4; ++i) {
                    float zv = 0.f;
                    if (n < 7) zv = relu_(acc1[n][i] + fb1v[n]);
                    const unsigned row = Rbase + 4u * lkg + (unsigned)i;
                    *(short*)&sAB[lidx(row, (unsigned)((16 * nn + (int)lrow) * 2))] = f2bf(zv);
                }
            }
            // consume as fc2 A-frags for kt = 2h, 2h+1
            #pragma unroll
            for (int q = 0; q < 2; ++q) {
                const int kt = 2 * h + q;
                short8 A2 = *(const short8*)&sAB[lidx(myrow, (unsigned)(q * 64) + lkg * 16u)];
                #pragma unroll
                for (int n = 0; n < 3; ++n) {
                    short8 b2 = f2p[(n * 4 + kt) * 64 + lane];
                    acc2[n] = __builtin_amdgcn_mfma_f32_16x16x32_bf16(A2, b2, acc2[n], 0, 0, 0);
                }
            }
        }

        // out (f32) -> this tile's rows, cols 0..35
        #pragma unroll
        for (int n = 0; n < 3; ++n) {
            const unsigned col = 16u * (unsigned)n + lrow;
            #pragma unroll
            for (int i = 0; i < 4; ++i) {
                if (col < 36u) {
                    const unsigned row = Rbase + 4u * lkg + (unsigned)i;
                    *(float*)&sAB[lidx(row, col * 4u)] = acc2[n][i] + fb2v[n];
                }
            }
        }
    }

    // ---- per-sample part losses from own out-row (cols 0..31) ----
    float o[32];
    #pragma unroll
    for (int b = 0; b < 8; ++b) {
        float4 v = *(const float4*)&sAB[lidx((unsigned)t, (unsigned)(b * 16))];
        o[4 * b + 0] = v.x; o[4 * b + 1] = v.y; o[4 * b + 2] = v.z; o[4 * b + 3] = v.w;
    }

    float sp[5], np[5];
    {
        float dxa = o[0] - o[28], dya = o[1] - o[29];
        float dxb = o[0] - o[30], dyb = o[1] - o[31];
        float pred = 0.5f * (sqrtf(dxa*dxa + dya*dya) + sqrtf(dxb*dxb + dyb*dyb));
        float gxa = pbx[0] - o[30];
        float gt = 0.5f * (pd1[0] + sqrtf(gxa * gxa + pgy[0] * pgy[0]));
        float e = pred - gt;
        sp[0] = e * e * pvf[0]; np[0] = pvf[0];
    }
    #pragma unroll
    for (int p = 0; p < 4; ++p) {
        const int a = 2 + 3 * p, b = a + 1, cc = a + 2;
        float dxa = o[2*a] - o[2*b],  dya = o[2*a+1] - o[2*b+1];
        float dxb = o[2*b] - o[2*cc], dyb = o[2*b+1] - o[2*cc+1];
        float pred = 0.5f * (sqrtf(dxa*dxa + dya*dya) + sqrtf(dxb*dxb + dyb*dyb));
        float gxa = pbx[p + 1] - o[2 * cc];
        float gt = 0.5f * (pd1[p + 1] + sqrtf(gxa * gxa + pgy[p + 1] * pgy[p + 1]));
        float e = pred - gt;
        sp[p + 1] = e * e * pvf[p + 1]; np[p + 1] = pvf[p + 1];
    }

    __syncthreads();   // all waves' out-rows complete

    // ---- coalesced x store + miss store + elementwise kp-loss ----
    const size_t blkBase = (size_t)blockIdx.x * (NT * 36);
    const float4* cin4 = (const float4*)(cin + blkBase);
    const int4*   tm4  = (const int4*)(tmask + blkBase);
    float4*       x4   = (float4*)(xout + blkBase);
    float*        mo   = missout + blkBase;

    float s1 = 0.f, s2 = 0.f;
    #pragma unroll
    for (int i = 0; i < 9; ++i) {
        int g4 = i * NT + t;
        unsigned g = 4u * (unsigned)g4;
        unsigned row = g / 36u;
        unsigned col = g - row * 36u;          // %4 == 0 -> one 16B block
        float4 xv = *(const float4*)&sAB[lidx(row, col * 4u)];
        float4 cv = cin4[g4];
        int4   mv = tm4[g4];
        x4[g4] = xv;
        mo[g + 0] = (cv.x != -1.f) ? 1.f : 0.f;
        mo[g + 1] = (cv.y != -1.f) ? 1.f : 0.f;
        mo[g + 2] = (cv.z != -1.f) ? 1.f : 0.f;
        mo[g + 3] = (cv.w != -1.f) ? 1.f : 0.f;
        float m0 = (float)mv.x, m1_ = (float)mv.y, m2_ = (float)mv.z, m3_ = (float)mv.w;
        float d0 = xv.x - cv.x, d1 = xv.y - cv.y, d2 = xv.z - cv.z, d3 = xv.w - cv.w;
        s1 += d0*d0*m0 + d1*d1*m1_ + d2*d2*m2_ + d3*d3*m3_;
        s2 += m0 + m1_ + m2_ + m3_;
    }

    // ---- block reduction of 12 scalars ----
    float rv[12] = { s1, s2, sp[0], np[0], sp[1], np[1],
                     sp[2], np[2], sp[3], np[3], sp[4], np[4] };
    #pragma unroll
    for (int v = 0; v < 12; ++v) {
        #pragma unroll
        for (int off = 32; off > 0; off >>= 1)
            rv[v] += __shfl_down(rv[v], off, 64);
    }
    const int wave = t >> 6, lane6 = t & 63;
    if (lane6 == 0) {
        #pragma unroll
        for (int v = 0; v < 12; ++v) sred[wave][v] = rv[v];
    }
    __syncthreads();
    if (t < 12) {
        float s = sred[0][t] + sred[1][t] + sred[2][t] + sred[3][t];
        partials[blockIdx.x * 12 + t] = s;
    }
}

__global__ __launch_bounds__(256) void kp_fin(const float* __restrict__ partials,
                                              float* __restrict__ total_out)
{
    __shared__ float sred[4][12];
    const int t = threadIdx.x;
    float rv[12];
    #pragma unroll
    for (int v = 0; v < 12; ++v) rv[v] = 0.f;
    for (int b = t; b < NB; b += 256) {
        #pragma unroll
        for (int v = 0; v < 12; ++v) rv[v] += partials[b * 12 + v];
    }
    #pragma unroll
    for (int v = 0; v < 12; ++v) {
        #pragma unroll
        for (int off = 32; off > 0; off >>= 1)
            rv[v] += __shfl_down(rv[v], off, 64);
    }
    const int wave = t >> 6, lane = t & 63;
    if (lane == 0) {
        #pragma unroll
        for (int v = 0; v < 12; ++v) sred[wave][v] = rv[v];
    }
    __syncthreads();
    if (t == 0) {
        float acc[12];
        #pragma unroll
        for (int v = 0; v < 12; ++v)
            acc[v] = sred[0][v] + sred[1][v] + sred[2][v] + sred[3][v];
        float total = acc[0] / acc[1];
        #pragma unroll
        for (int p = 0; p < 5; ++p) {
            float s = acc[2 + 2 * p], n = acc[3 + 2 * p];
            total += (n > 0.f) ? (s / fmaxf(n, 1.f)) : 0.f;
        }
        total_out[0] = total;
    }
}

extern "C" void kernel_launch(void* const* d_in, const int* in_sizes, int n_in,
                              void* d_out, int out_size, void* d_ws, size_t ws_size,
                              hipStream_t stream)
{
    const float* cin   = (const float*)d_in[0];
    const int*   tmask = (const int*)  d_in[1];
    const float* w1  = (const float*)d_in[2];
    const float* b1  = (const float*)d_in[3];
    const float* g1  = (const float*)d_in[4];
    const float* bt1 = (const float*)d_in[5];
    const float* m1  = (const float*)d_in[6];
    const float* v1  = (const float*)d_in[7];
    const float* w2  = (const float*)d_in[8];
    const float* b2  = (const float*)d_in[9];
    const float* g2  = (const float*)d_in[10];
    const float* bt2 = (const float*)d_in[11];
    const float* m2  = (const float*)d_in[12];
    const float* v2  = (const float*)d_in[13];
    const float* w3  = (const float*)d_in[14];
    const float* b3  = (const float*)d_in[15];
    const float* g3  = (const float*)d_in[16];
    const float* bt3 = (const float*)d_in[17];
    const float* m3  = (const float*)d_in[18];
    const float* v3  = (const float*)d_in[19];
    const float* fw1 = (const float*)d_in[20];
    const float* fb1 = (const float*)d_in[21];
    const float* fw2 = (const float*)d_in[22];
    const float* fb2 = (const float*)d_in[23];

    float* xout     = (float*)d_out;                       // [B,36]
    float* total    = (float*)d_out + (size_t)BTOT * 36;   // scalar
    float* missout  = total + 1;                           // [B,36] as f32 0/1

    float* wsf      = (float*)d_ws;
    short* fr1      = (short*)((char*)d_ws + FR1_BYTE);
    short* fr2      = (short*)((char*)d_ws + FR2_BYTE);
    float* partials = (float*)((char*)d_ws + PART_BYTE);   // [NB,12]

    kp_setup<<<1, 256, 0, stream>>>(
        w1, b1, g1, bt1, m1, v1,
        w2, b2, g2, bt2, m2, v2,
        w3, b3, g3, bt3, m3, v3,
        fw1, fw2, wsf, fr1, fr2);

    kp_fwd<<<NB, NT, 0, stream>>>(cin, tmask, wsf, fr1, fr2,
        fb1, fb2, xout, missout, partials);

    kp_fin<<<1, 256, 0, stream>>>(partials, total);
}

// Round 7
// 128.015 us; speedup vs baseline: 1.2485x; 1.0038x over previous
//
#include <hip/hip_runtime.h>

#define NB   1024
#define NT   256
#define BTOT 262144   // NB*NT == B

typedef __attribute__((ext_vector_type(8))) short short8;
typedef __attribute__((ext_vector_type(4))) float f32x4;

__device__ __forceinline__ float relu_(float x) { return fmaxf(x, 0.0f); }

__device__ __forceinline__ short f2bf(float x) {   // RNE f32->bf16
    unsigned u = __float_as_uint(x);
    unsigned r = (u + 0x7FFFu + ((u >> 16) & 1u)) >> 16;
    return (short)r;
}

// 144B rows, LINEAR. 144 B = 36 dwords = 4 mod 32 banks: consecutive rows are
// naturally staggered by one 16B block, so column reads (A-frags: 16 rows,
// same block) spread across banks without an explicit swizzle.
__device__ __forceinline__ unsigned lidx(unsigned row, unsigned byteoff) {
    return row * 144u + byteoff;
}

// d_ws float-offset layout:
//   W1 0..179 | B1 180..189 | A0 190..199 | W2 200..599 | B2 600..619
//   W3 620..1819 | B3 1820..1849
// byte 7424:  fc1 frags (14*512 shorts)
// byte 21760: fc2 frags (12*512 shorts)
// byte 34048: partials [NB*12] f32
#define FR1_BYTE 7424
#define FR2_BYTE 21760
#define PART_BYTE 34048

__global__ __launch_bounds__(256) void kp_setup(
    const float* __restrict__ w1, const float* __restrict__ b1,
    const float* __restrict__ g1, const float* __restrict__ bt1,
    const float* __restrict__ m1, const float* __restrict__ v1,
    const float* __restrict__ w2, const float* __restrict__ b2,
    const float* __restrict__ g2, const float* __restrict__ bt2,
    const float* __restrict__ m2, const float* __restrict__ v2,
    const float* __restrict__ w3, const float* __restrict__ b3,
    const float* __restrict__ g3, const float* __restrict__ bt3,
    const float* __restrict__ m3, const float* __restrict__ v3,
    const float* __restrict__ fw1, const float* __restrict__ fw2,
    float* __restrict__ wsf, short* __restrict__ fr1, short* __restrict__ fr2)
{
    const int t = threadIdx.x;
    if (t < 10) {
        float s  = g1[t] * rsqrtf(v1[t] + 1e-5f);
        float bb = (b1[t] - m1[t]) * s + bt1[t];
        wsf[180 + t] = bb;
        wsf[190 + t] = relu_(bb);
        for (int i = 0; i < 18; ++i) wsf[t * 18 + i] = w1[t * 18 + i] * s;
    } else if (t >= 64 && t < 84) {
        int o = t - 64;
        float s = g2[o] * rsqrtf(v2[o] + 1e-5f);
        wsf[600 + o] = (b2[o] - m2[o]) * s + bt2[o];
        for (int i = 0; i < 20; ++i) wsf[200 + o * 20 + i] = w2[o * 20 + i] * s;
    } else if (t >= 128 && t < 158) {
        int o = t - 128;
        float s = g3[o] * rsqrtf(v3[o] + 1e-5f);
        wsf[1820 + o] = (b3[o] - m3[o]) * s + bt3[o];
        for (int i = 0; i < 40; ++i) wsf[620 + o * 40 + i] = w3[o * 40 + i] * s;
    }
    // fc1 B-frags: B1[k][j] = fw1[j*60+k]
    for (int e = t; e < 14 * 512; e += 256) {
        int pos = e >> 9, l = (e >> 3) & 63, j = e & 7;
        int n = pos >> 1, kt = pos & 1;
        int col = 16 * n + (l & 15);
        int k   = kt * 32 + (l >> 4) * 8 + j;
        float v = (col < 100 && k < 60) ? fw1[col * 60 + k] : 0.f;
        fr1[e] = f2bf(v);
    }
    // fc2 B-frags: B2[k][cc] = fw2[cc*100+k]
    for (int e = t; e < 12 * 512; e += 256) {
        int pos = e >> 9, l = (e >> 3) & 63, j = e & 7;
        int n = pos >> 2, kt = pos & 3;
        int col = 16 * n + (l & 15);
        int k   = kt * 32 + (l >> 4) * 8 + j;
        float v = (col < 36 && k < 100) ? fw2[col * 100 + k] : 0.f;
        fr2[e] = f2bf(v);
    }
}

__global__ __launch_bounds__(NT) void kp_fwd(
    const float* __restrict__ cin, const int* __restrict__ tmask,
    const float* __restrict__ wf,          // folded weights (uniform -> s_load)
    const short* __restrict__ fr1,         // fc1 B-frags
    const short* __restrict__ fr2,         // fc2 B-frags
    const float* __restrict__ fb1, const float* __restrict__ fb2,
    float* __restrict__ xout, float* __restrict__ missout,
    float* __restrict__ partials)
{
    __shared__ __align__(16) unsigned char sAB[NT * 144];   // 36KB row buffer
    __shared__ float sred[4][12];

    const int t = threadIdx.x;
    const int tid = blockIdx.x * NT + t;
    const float* cp = cin + (size_t)tid * 36;

    // ---- conv1 input: c[36] lives ONLY through conv1 (loss-prep moved to epilogue)
    {
        float c[36];
        #pragma unroll
        for (int i = 0; i < 9; ++i)
            *(float4*)(c + 4 * i) = *(const float4*)(cp + 4 * i);

        float a1[10][3];
        #pragma unroll
        for (int o = 0; o < 10; ++o) {
            float acc0 = wf[180 + o], acc1 = acc0;
            #pragma unroll
            for (int i = 0; i < 18; ++i) {
                float w = wf[o * 18 + i];
                acc0 += w * c[2 * i];
                acc1 += w * c[2 * i + 1];
            }
            a1[o][0] = wf[190 + o];
            a1[o][1] = relu_(acc0);
            a1[o][2] = relu_(acc1);
        }

        float a2[20][3];
        #pragma unroll
        for (int o = 0; o < 20; ++o) {
            float bb = wf[600 + o];
            float t0 = bb, t1 = bb, t2 = bb;
            #pragma unroll
            for (int i = 0; i < 10; ++i) {
                float wa = wf[200 + o * 20 + i * 2];
                float wb = wf[200 + o * 20 + i * 2 + 1];
                float p0 = a1[i][0], p1 = a1[i][1], p2 = a1[i][2];
                t0 += p0 * wa + p1 * wb;
                t1 += p1 * wa + p2 * wb;
                t2 += p2 * wa + p0 * wb;   // pos3 == pos0
            }
            a2[o][0] = relu_(t0);
            a2[o][1] = relu_(t1);
            a2[o][2] = relu_(t2);
        }

        // conv3: rolled over o; one packed bf16-pair dword to own LDS row per o
        #pragma unroll 1
        for (int o = 0; o < 30; ++o) {
            float bb = wf[1820 + o];
            float t0 = bb, t1 = bb;
            #pragma unroll
            for (int i = 0; i < 20; ++i) {
                float wa = wf[620 + o * 40 + i * 2];
                float wb = wf[620 + o * 40 + i * 2 + 1];
                t0 += a2[i][0] * wa + a2[i][1] * wb;
                t1 += a2[i][1] * wa + a2[i][2] * wb;
            }
            unsigned pk = ((unsigned)(unsigned short)f2bf(relu_(t0))) |
                          (((unsigned)(unsigned short)f2bf(relu_(t1))) << 16);
            *(unsigned*)&sAB[lidx((unsigned)t, (unsigned)(o * 4))] = pk;
        }
        // zero cols 60..63 (bytes 120..127)
        *(unsigned*)&sAB[lidx((unsigned)t, 120u)] = 0u;
        *(unsigned*)&sAB[lidx((unsigned)t, 124u)] = 0u;
    }

    // ---- MFMA FC section (wave-private rows; in-order DS => no barriers) ----
    const int lane = t & 63;
    const unsigned wbase = (unsigned)(t & ~63);
    const unsigned lrow  = (unsigned)(lane & 15);
    const unsigned lkg   = (unsigned)(lane >> 4);   // 0..3

    float fb1v[7], fb2v[3];
    #pragma unroll
    for (int n = 0; n < 7; ++n) { int j = 16 * n + (int)lrow; fb1v[n] = (j < 100) ? fb1[j] : 0.f; }
    #pragma unroll
    for (int n = 0; n < 3; ++n) { int cc = 16 * n + (int)lrow; fb2v[n] = (cc < 36) ? fb2[cc] : 0.f; }

    const short8* f1p = (const short8*)fr1;   // [pos*64+lane]
    const short8* f2p = (const short8*)fr2;

    #pragma unroll 1
    for (int m = 0; m < 4; ++m) {
        const unsigned Rbase = wbase + 16u * (unsigned)m;
        const unsigned myrow = Rbase + lrow;

        short8 A1a = *(const short8*)&sAB[lidx(myrow, lkg * 16u)];
        short8 A1b = *(const short8*)&sAB[lidx(myrow, 64u + lkg * 16u)];

        f32x4 acc1[7];
        #pragma unroll
        for (int n = 0; n < 7; ++n) acc1[n] = (f32x4){0.f, 0.f, 0.f, 0.f};
        #pragma unroll
        for (int n = 0; n < 7; ++n) {
            short8 b0 = f1p[(n * 2 + 0) * 64 + lane];
            acc1[n] = __builtin_amdgcn_mfma_f32_16x16x32_bf16(A1a, b0, acc1[n], 0, 0, 0);
            short8 b1 = f1p[(n * 2 + 1) * 64 + lane];
            acc1[n] = __builtin_amdgcn_mfma_f32_16x16x32_bf16(A1b, b1, acc1[n], 0, 0, 0);
        }

        f32x4 acc2[3];
        #pragma unroll
        for (int n = 0; n < 3; ++n) acc2[n] = (f32x4){0.f, 0.f, 0.f, 0.f};

        #pragma unroll
        for (int h = 0; h < 2; ++h) {
            // write z cols [64h..64h+63] (bf16) into this tile's 16 rows
            #pragma unroll
            for (int nn = 0; nn < 4; ++nn) {
                const int n = 4 * h + nn;
                #pragma unroll
                for (int i = 0; i < 4; ++i) {
                    float zv = 0.f;
                    if (n < 7) zv = relu_(acc1[n][i] + fb1v[n]);
                    const unsigned row = Rbase + 4u * lkg + (unsigned)i;
                    *(short*)&sAB[lidx(row, (unsigned)((16 * nn + (int)lrow) * 2))] = f2bf(zv);
                }
            }
            // consume as fc2 A-frags for kt = 2h, 2h+1
            #pragma unroll
            for (int q = 0; q < 2; ++q) {
                const int kt = 2 * h + q;
                short8 A2 = *(const short8*)&sAB[lidx(myrow, (unsigned)(q * 64) + lkg * 16u)];
                #pragma unroll
                for (int n = 0; n < 3; ++n) {
                    short8 b2 = f2p[(n * 4 + kt) * 64 + lane];
                    acc2[n] = __builtin_amdgcn_mfma_f32_16x16x32_bf16(A2, b2, acc2[n], 0, 0, 0);
                }
            }
        }

        // out (f32) -> this tile's rows, cols 0..35
        #pragma unroll
        for (int n = 0; n < 3; ++n) {
            const unsigned col = 16u * (unsigned)n + lrow;
            #pragma unroll
            for (int i = 0; i < 4; ++i) {
                if (col < 36u) {
                    const unsigned row = Rbase + 4u * lkg + (unsigned)i;
                    *(float*)&sAB[lidx(row, col * 4u)] = acc2[n][i] + fb2v[n];
                }
            }
        }
    }

    // ---- epilogue loss-prep: reload c[0..31] (L2/L3-hot), read own out-row ----
    float cg[32];
    #pragma unroll
    for (int i = 0; i < 8; ++i)
        *(float4*)(cg + 4 * i) = *(const float4*)(cp + 4 * i);

    float o[32];
    #pragma unroll
    for (int b = 0; b < 8; ++b) {
        float4 v = *(const float4*)&sAB[lidx((unsigned)t, (unsigned)(b * 16))];
        o[4 * b + 0] = v.x; o[4 * b + 1] = v.y; o[4 * b + 2] = v.z; o[4 * b + 3] = v.w;
    }

    float sp[5], np[5];
    {   // head (0,14,15); gt mixes x[:,15,0] and c[:,15,1] (faithful)
        float dxa = o[0] - o[28], dya = o[1] - o[29];
        float dxb = o[0] - o[30], dyb = o[1] - o[31];
        float pred = 0.5f * (sqrtf(dxa*dxa + dya*dya) + sqrtf(dxb*dxb + dyb*dyb));
        float cxa = cg[0] - cg[28], cya = cg[1] - cg[29];
        float gxa = cg[0] - o[30],  gya = cg[1] - cg[31];
        float gt = 0.5f * (sqrtf(cxa*cxa + cya*cya) + sqrtf(gxa*gxa + gya*gya));
        float vf = (cg[0] != -1.f && cg[28] != -1.f && cg[30] != -1.f) ? 1.f : 0.f;
        float e = pred - gt;
        sp[0] = e * e * vf; np[0] = vf;
    }
    #pragma unroll
    for (int p = 0; p < 4; ++p) {
        const int a = 2 + 3 * p, b = a + 1, cc = a + 2;
        float dxa = o[2*a] - o[2*b],  dya = o[2*a+1] - o[2*b+1];
        float dxb = o[2*b] - o[2*cc], dyb = o[2*b+1] - o[2*cc+1];
        float pred = 0.5f * (sqrtf(dxa*dxa + dya*dya) + sqrtf(dxb*dxb + dyb*dyb));
        float cxa = cg[2*a] - cg[2*b], cya = cg[2*a+1] - cg[2*b+1];
        float gxa = cg[2*b] - o[2*cc], gya = cg[2*b+1] - cg[2*cc+1];
        float gt = 0.5f * (sqrtf(cxa*cxa + cya*cya) + sqrtf(gxa*gxa + gya*gya));
        float vf = (cg[2*a] != -1.f && cg[2*b] != -1.f && cg[2*cc] != -1.f) ? 1.f : 0.f;
        float e = pred - gt;
        sp[p + 1] = e * e * vf; np[p + 1] = vf;
    }

    __syncthreads();   // all waves' out-rows complete

    // ---- coalesced x store + miss store + elementwise kp-loss ----
    const size_t blkBase = (size_t)blockIdx.x * (NT * 36);
    const float4* cin4 = (const float4*)(cin + blkBase);
    const int4*   tm4  = (const int4*)(tmask + blkBase);
    float4*       x4   = (float4*)(xout + blkBase);
    float*        mo   = missout + blkBase;

    float s1 = 0.f, s2 = 0.f;
    #pragma unroll
    for (int i = 0; i < 9; ++i) {
        int g4 = i * NT + t;
        unsigned g = 4u * (unsigned)g4;
        unsigned row = g / 36u;
        unsigned col = g - row * 36u;          // %4 == 0 -> one 16B block
        float4 xv = *(const float4*)&sAB[lidx(row, col * 4u)];
        float4 cv = cin4[g4];
        int4   mv = tm4[g4];
        x4[g4] = xv;
        mo[g + 0] = (cv.x != -1.f) ? 1.f : 0.f;
        mo[g + 1] = (cv.y != -1.f) ? 1.f : 0.f;
        mo[g + 2] = (cv.z != -1.f) ? 1.f : 0.f;
        mo[g + 3] = (cv.w != -1.f) ? 1.f : 0.f;
        float m0 = (float)mv.x, m1_ = (float)mv.y, m2_ = (float)mv.z, m3_ = (float)mv.w;
        float d0 = xv.x - cv.x, d1 = xv.y - cv.y, d2 = xv.z - cv.z, d3 = xv.w - cv.w;
        s1 += d0*d0*m0 + d1*d1*m1_ + d2*d2*m2_ + d3*d3*m3_;
        s2 += m0 + m1_ + m2_ + m3_;
    }

    // ---- block reduction of 12 scalars ----
    float rv[12] = { s1, s2, sp[0], np[0], sp[1], np[1],
                     sp[2], np[2], sp[3], np[3], sp[4], np[4] };
    #pragma unroll
    for (int v = 0; v < 12; ++v) {
        #pragma unroll
        for (int off = 32; off > 0; off >>= 1)
            rv[v] += __shfl_down(rv[v], off, 64);
    }
    const int wave = t >> 6, lane6 = t & 63;
    if (lane6 == 0) {
        #pragma unroll
        for (int v = 0; v < 12; ++v) sred[wave][v] = rv[v];
    }
    __syncthreads();
    if (t < 12) {
        float s = sred[0][t] + sred[1][t] + sred[2][t] + sred[3][t];
        partials[blockIdx.x * 12 + t] = s;
    }
}

__global__ __launch_bounds__(256) void kp_fin(const float* __restrict__ partials,
                                              float* __restrict__ total_out)
{
    __shared__ float sred[4][12];
    const int t = threadIdx.x;
    float rv[12];
    #pragma unroll
    for (int v = 0; v < 12; ++v) rv[v] = 0.f;
    for (int b = t; b < NB; b += 256) {
        #pragma unroll
        for (int v = 0; v < 12; ++v) rv[v] += partials[b * 12 + v];
    }
    #pragma unroll
    for (int v = 0; v < 12; ++v) {
        #pragma unroll
        for (int off = 32; off > 0; off >>= 1)
            rv[v] += __shfl_down(rv[v], off, 64);
    }
    const int wave = t >> 6, lane = t & 63;
    if (lane == 0) {
        #pragma unroll
        for (int v = 0; v < 12; ++v) sred[wave][v] = rv[v];
    }
    __syncthreads();
    if (t == 0) {
        float acc[12];
        #pragma unroll
        for (int v = 0; v < 12; ++v)
            acc[v] = sred[0][v] + sred[1][v] + sred[2][v] + sred[3][v];
        float total = acc[0] / acc[1];
        #pragma unroll
        for (int p = 0; p < 5; ++p) {
            float s = acc[2 + 2 * p], n = acc[3 + 2 * p];
            total += (n > 0.f) ? (s / fmaxf(n, 1.f)) : 0.f;
        }
        total_out[0] = total;
    }
}

extern "C" void kernel_launch(void* const* d_in, const int* in_sizes, int n_in,
                              void* d_out, int out_size, void* d_ws, size_t ws_size,
                              hipStream_t stream)
{
    const float* cin   = (const float*)d_in[0];
    const int*   tmask = (const int*)  d_in[1];
    const float* w1  = (const float*)d_in[2];
    const float* b1  = (const float*)d_in[3];
    const float* g1  = (const float*)d_in[4];
    const float* bt1 = (const float*)d_in[5];
    const float* m1  = (const float*)d_in[6];
    const float* v1  = (const float*)d_in[7];
    const float* w2  = (const float*)d_in[8];
    const float* b2  = (const float*)d_in[9];
    const float* g2  = (const float*)d_in[10];
    const float* bt2 = (const float*)d_in[11];
    const float* m2  = (const float*)d_in[12];
    const float* v2  = (const float*)d_in[13];
    const float* w3  = (const float*)d_in[14];
    const float* b3  = (const float*)d_in[15];
    const float* g3  = (const float*)d_in[16];
    const float* bt3 = (const float*)d_in[17];
    const float* m3  = (const float*)d_in[18];
    const float* v3  = (const float*)d_in[19];
    const float* fw1 = (const float*)d_in[20];
    const float* fb1 = (const float*)d_in[21];
    const float* fw2 = (const float*)d_in[22];
    const float* fb2 = (const float*)d_in[23];

    float* xout     = (float*)d_out;                       // [B,36]
    float* total    = (float*)d_out + (size_t)BTOT * 36;   // scalar
    float* missout  = total + 1;                           // [B,36] as f32 0/1

    float* wsf      = (float*)d_ws;
    short* fr1      = (short*)((char*)d_ws + FR1_BYTE);
    short* fr2      = (short*)((char*)d_ws + FR2_BYTE);
    float* partials = (float*)((char*)d_ws + PART_BYTE);   // [NB,12]

    kp_setup<<<1, 256, 0, stream>>>(
        w1, b1, g1, bt1, m1, v1,
        w2, b2, g2, bt2, m2, v2,
        w3, b3, g3, bt3, m3, v3,
        fw1, fw2, wsf, fr1, fr2);

    kp_fwd<<<NB, NT, 0, stream>>>(cin, tmask, wsf, fr1, fr2,
        fb1, fb2, xout, missout, partials);

    kp_fin<<<1, 256, 0, stream>>>(partials, total);
}

// Round 9
// 101.620 us; speedup vs baseline: 1.5728x; 1.2597x over previous
//
#include <hip/hip_runtime.h>

#define NB   1024
#define NT   256
#define BTOT 262144   // NB*NT == B

typedef __attribute__((ext_vector_type(8))) short short8;
typedef __attribute__((ext_vector_type(4))) float f32x4;

__device__ __forceinline__ float relu_(float x) { return fmaxf(x, 0.0f); }

__device__ __forceinline__ short f2bf(float x) {   // RNE f32->bf16
    unsigned u = __float_as_uint(x);
    unsigned r = (u + 0x7FFFu + ((u >> 16) & 1u)) >> 16;
    return (short)r;
}

// 144B LDS rows, LINEAR (144 B = 4 dwords mod 32 banks: natural stagger).
__device__ __forceinline__ unsigned lidx(unsigned row, unsigned byteoff) {
    return row * 144u + byteoff;
}

// d_ws float-offset layout:
//   W1 0..179 | B1 180..189 | A0 190..199 | W2 200..599 | B2 600..619
//   W3 620..1819 | B3 1820..1849
#define FR1_BYTE 7424
#define FR2_BYTE 21760
#define PART_BYTE 34048

// f staging: BLOCK-LOCAL inside the x output region. Block b owns x floats
// [b*9216, (b+1)*9216); its f occupies the first 2048 uint4 (32KB) of that
// same slice as [chunk 0..7][256 samples]. kp_fc reads only its own block's
// slice and overwrites it with x AFTER __syncthreads() -> no cross-block race.
#define FBLK_U4 2304   // uint4 per block of x region (9216 floats / 4)

__global__ __launch_bounds__(256) void kp_setup(
    const float* __restrict__ w1, const float* __restrict__ b1,
    const float* __restrict__ g1, const float* __restrict__ bt1,
    const float* __restrict__ m1, const float* __restrict__ v1,
    const float* __restrict__ w2, const float* __restrict__ b2,
    const float* __restrict__ g2, const float* __restrict__ bt2,
    const float* __restrict__ m2, const float* __restrict__ v2,
    const float* __restrict__ w3, const float* __restrict__ b3,
    const float* __restrict__ g3, const float* __restrict__ bt3,
    const float* __restrict__ m3, const float* __restrict__ v3,
    const float* __restrict__ fw1, const float* __restrict__ fw2,
    float* __restrict__ wsf, short* __restrict__ fr1, short* __restrict__ fr2)
{
    const int t = threadIdx.x;
    if (t < 10) {
        float s  = g1[t] * rsqrtf(v1[t] + 1e-5f);
        float bb = (b1[t] - m1[t]) * s + bt1[t];
        wsf[180 + t] = bb;
        wsf[190 + t] = relu_(bb);
        for (int i = 0; i < 18; ++i) wsf[t * 18 + i] = w1[t * 18 + i] * s;
    } else if (t >= 64 && t < 84) {
        int o = t - 64;
        float s = g2[o] * rsqrtf(v2[o] + 1e-5f);
        wsf[600 + o] = (b2[o] - m2[o]) * s + bt2[o];
        for (int i = 0; i < 20; ++i) wsf[200 + o * 20 + i] = w2[o * 20 + i] * s;
    } else if (t >= 128 && t < 158) {
        int o = t - 128;
        float s = g3[o] * rsqrtf(v3[o] + 1e-5f);
        wsf[1820 + o] = (b3[o] - m3[o]) * s + bt3[o];
        for (int i = 0; i < 40; ++i) wsf[620 + o * 40 + i] = w3[o * 40 + i] * s;
    }
    // fc1 B-frags: B1[k][j] = fw1[j*60+k]
    for (int e = t; e < 14 * 512; e += 256) {
        int pos = e >> 9, l = (e >> 3) & 63, j = e & 7;
        int n = pos >> 1, kt = pos & 1;
        int col = 16 * n + (l & 15);
        int k   = kt * 32 + (l >> 4) * 8 + j;
        float v = (col < 100 && k < 60) ? fw1[col * 60 + k] : 0.f;
        fr1[e] = f2bf(v);
    }
    // fc2 B-frags: B2[k][cc] = fw2[cc*100+k]
    for (int e = t; e < 12 * 512; e += 256) {
        int pos = e >> 9, l = (e >> 3) & 63, j = e & 7;
        int n = pos >> 2, kt = pos & 3;
        int col = 16 * n + (l & 15);
        int k   = kt * 32 + (l >> 4) * 8 + j;
        float v = (col < 36 && k < 100) ? fw2[col * 100 + k] : 0.f;
        fr2[e] = f2bf(v);
    }
}

// ---------------- Kernel A: convs only (no LDS, no MFMA) ----------------
__global__ __launch_bounds__(NT) void kp_conv(
    const float* __restrict__ cin,
    const float* __restrict__ wf,
    float* xout_region)                    // f staged block-locally here
{
    const int t = threadIdx.x;
    const int tid = blockIdx.x * NT + t;
    const float* cp = cin + (size_t)tid * 36;
    uint4* fblk = (uint4*)xout_region + (size_t)blockIdx.x * FBLK_U4;

    float c[36];
    #pragma unroll
    for (int i = 0; i < 9; ++i)
        *(float4*)(c + 4 * i) = *(const float4*)(cp + 4 * i);

    float a1[10][3];
    #pragma unroll
    for (int o = 0; o < 10; ++o) {
        float acc0 = wf[180 + o], acc1 = acc0;
        #pragma unroll
        for (int i = 0; i < 18; ++i) {
            float w = wf[o * 18 + i];
            acc0 += w * c[2 * i];
            acc1 += w * c[2 * i + 1];
        }
        a1[o][0] = wf[190 + o];
        a1[o][1] = relu_(acc0);
        a1[o][2] = relu_(acc1);
    }
    float a2[20][3];
    #pragma unroll
    for (int o = 0; o < 20; ++o) {
        float bb = wf[600 + o];
        float t0 = bb, t1 = bb, t2 = bb;
        #pragma unroll
        for (int i = 0; i < 10; ++i) {
            float wa = wf[200 + o * 20 + i * 2];
            float wb = wf[200 + o * 20 + i * 2 + 1];
            float p0 = a1[i][0], p1 = a1[i][1], p2 = a1[i][2];
            t0 += p0 * wa + p1 * wb;
            t1 += p1 * wa + p2 * wb;
            t2 += p2 * wa + p0 * wb;   // pos3 == pos0
        }
        a2[o][0] = relu_(t0);
        a2[o][1] = relu_(t1);
        a2[o][2] = relu_(t2);
    }
    // conv3: 4 channels per 16B chunk, block-local chunk-major (coalesced)
    #pragma unroll 1
    for (int k = 0; k < 7; ++k) {
        unsigned pk[4];
        #pragma unroll
        for (int j = 0; j < 4; ++j) {
            const int o = 4 * k + j;
            float bb = wf[1820 + o];
            float t0 = bb, t1 = bb;
            #pragma unroll
            for (int i = 0; i < 20; ++i) {
                float wa = wf[620 + o * 40 + i * 2];
                float wb = wf[620 + o * 40 + i * 2 + 1];
                t0 += a2[i][0] * wa + a2[i][1] * wb;
                t1 += a2[i][1] * wa + a2[i][2] * wb;
            }
            pk[j] = ((unsigned)(unsigned short)f2bf(relu_(t0))) |
                    (((unsigned)(unsigned short)f2bf(relu_(t1))) << 16);
        }
        fblk[k * NT + t] = make_uint4(pk[0], pk[1], pk[2], pk[3]);
    }
    {   // chunk 7: channels 28,29 + zero pad (cols 60..63)
        unsigned pk[2];
        #pragma unroll
        for (int j = 0; j < 2; ++j) {
            const int o = 28 + j;
            float bb = wf[1820 + o];
            float t0 = bb, t1 = bb;
            #pragma unroll
            for (int i = 0; i < 20; ++i) {
                float wa = wf[620 + o * 40 + i * 2];
                float wb = wf[620 + o * 40 + i * 2 + 1];
                t0 += a2[i][0] * wa + a2[i][1] * wb;
                t1 += a2[i][1] * wa + a2[i][2] * wb;
            }
            pk[j] = ((unsigned)(unsigned short)f2bf(relu_(t0))) |
                    (((unsigned)(unsigned short)f2bf(relu_(t1))) << 16);
        }
        fblk[7 * NT + t] = make_uint4(pk[0], pk[1], 0u, 0u);
    }
}

// ---------------- Kernel B: MFMA FC + losses + outputs ----------------
__global__ __launch_bounds__(NT) void kp_fc(
    const float* __restrict__ cin, const int* __restrict__ tmask,
    const short* __restrict__ fr1, const short* __restrict__ fr2,
    const float* __restrict__ fb1, const float* __restrict__ fb2,
    float* xout,                           // own-block f source, then x dest
    float* __restrict__ missout,
    float* __restrict__ partials)
{
    __shared__ __align__(16) unsigned char sAB[NT * 144];   // 36KB row buffer
    __shared__ float sred[4][12];

    const int t = threadIdx.x;
    const int tid = blockIdx.x * NT + t;
    const float* cp = cin + (size_t)tid * 36;
    const short8* fblk = (const short8*)((const uint4*)xout + (size_t)blockIdx.x * FBLK_U4);

    const int lane = t & 63;
    const unsigned wbase = (unsigned)(t & ~63);
    const unsigned lrow  = (unsigned)(lane & 15);
    const unsigned lkg   = (unsigned)(lane >> 4);   // 0..3

    float fb1v[7], fb2v[3];
    #pragma unroll
    for (int n = 0; n < 7; ++n) { int j = 16 * n + (int)lrow; fb1v[n] = (j < 100) ? fb1[j] : 0.f; }
    #pragma unroll
    for (int n = 0; n < 3; ++n) { int cc = 16 * n + (int)lrow; fb2v[n] = (cc < 36) ? fb2[cc] : 0.f; }

    const short8* f1p = (const short8*)fr1;   // [pos*64+lane]
    const short8* f2p = (const short8*)fr2;

    #pragma unroll 1
    for (int m = 0; m < 4; ++m) {
        const unsigned Rbase = wbase + 16u * (unsigned)m;   // block-local row
        const unsigned myrow = Rbase + lrow;

        // A-frags from own block's staged f: chunk lkg and chunk 4+lkg
        short8 A1a = fblk[lkg * NT + myrow];
        short8 A1b = fblk[(lkg + 4u) * NT + myrow];

        f32x4 acc2[3];
        #pragma unroll
        for (int n = 0; n < 3; ++n) acc2[n] = (f32x4){0.f, 0.f, 0.f, 0.f};

        #pragma unroll
        for (int h = 0; h < 2; ++h) {
            // fc1 for this half's n-range only (acc1 halves never co-live)
            f32x4 acc1[4];
            #pragma unroll
            for (int nn = 0; nn < 4; ++nn) {
                const int n = 4 * h + nn;
                acc1[nn] = (f32x4){0.f, 0.f, 0.f, 0.f};
                if (n < 7) {
                    short8 b0 = f1p[(n * 2 + 0) * 64 + lane];
                    acc1[nn] = __builtin_amdgcn_mfma_f32_16x16x32_bf16(A1a, b0, acc1[nn], 0, 0, 0);
                    short8 b1 = f1p[(n * 2 + 1) * 64 + lane];
                    acc1[nn] = __builtin_amdgcn_mfma_f32_16x16x32_bf16(A1b, b1, acc1[nn], 0, 0, 0);
                }
            }
            // write z cols [64h..64h+63] (bf16) into this tile's 16 rows
            #pragma unroll
            for (int nn = 0; nn < 4; ++nn) {
                const int n = 4 * h + nn;
                #pragma unroll
                for (int i = 0; i < 4; ++i) {
                    float zv = 0.f;
                    if (n < 7) zv = relu_(acc1[nn][i] + fb1v[n]);
                    const unsigned row = Rbase + 4u * lkg + (unsigned)i;
                    *(short*)&sAB[lidx(row, (unsigned)((16 * nn + (int)lrow) * 2))] = f2bf(zv);
                }
            }
            // consume as fc2 A-frags for kt = 2h, 2h+1
            #pragma unroll
            for (int q = 0; q < 2; ++q) {
                const int kt = 2 * h + q;
                short8 A2 = *(const short8*)&sAB[lidx(myrow, (unsigned)(q * 64) + lkg * 16u)];
                #pragma unroll
                for (int n = 0; n < 3; ++n) {
                    short8 b2 = f2p[(n * 4 + kt) * 64 + lane];
                    acc2[n] = __builtin_amdgcn_mfma_f32_16x16x32_bf16(A2, b2, acc2[n], 0, 0, 0);
                }
            }
        }

        // out (f32) -> this tile's rows, cols 0..35
        #pragma unroll
        for (int n = 0; n < 3; ++n) {
            const unsigned col = 16u * (unsigned)n + lrow;
            #pragma unroll
            for (int i = 0; i < 4; ++i) {
                if (col < 36u) {
                    const unsigned row = Rbase + 4u * lkg + (unsigned)i;
                    *(float*)&sAB[lidx(row, col * 4u)] = acc2[n][i] + fb2v[n];
                }
            }
        }
    }

    // ---- per-sample part losses: own out-row + c reload (L2/L3-hot) ----
    float cg[32];
    #pragma unroll
    for (int i = 0; i < 8; ++i)
        *(float4*)(cg + 4 * i) = *(const float4*)(cp + 4 * i);

    float o[32];
    #pragma unroll
    for (int b = 0; b < 8; ++b) {
        float4 v = *(const float4*)&sAB[lidx((unsigned)t, (unsigned)(b * 16))];
        o[4 * b + 0] = v.x; o[4 * b + 1] = v.y; o[4 * b + 2] = v.z; o[4 * b + 3] = v.w;
    }

    float sp[5], np[5];
    {   // head (0,14,15); gt mixes x[:,15,0] and c[:,15,1] (faithful)
        float dxa = o[0] - o[28], dya = o[1] - o[29];
        float dxb = o[0] - o[30], dyb = o[1] - o[31];
        float pred = 0.5f * (sqrtf(dxa*dxa + dya*dya) + sqrtf(dxb*dxb + dyb*dyb));
        float cxa = cg[0] - cg[28], cya = cg[1] - cg[29];
        float gxa = cg[0] - o[30],  gya = cg[1] - cg[31];
        float gt = 0.5f * (sqrtf(cxa*cxa + cya*cya) + sqrtf(gxa*gxa + gya*gya));
        float vf = (cg[0] != -1.f && cg[28] != -1.f && cg[30] != -1.f) ? 1.f : 0.f;
        float e = pred - gt;
        sp[0] = e * e * vf; np[0] = vf;
    }
    #pragma unroll
    for (int p = 0; p < 4; ++p) {
        const int a = 2 + 3 * p, b = a + 1, cc = a + 2;
        float dxa = o[2*a] - o[2*b],  dya = o[2*a+1] - o[2*b+1];
        float dxb = o[2*b] - o[2*cc], dyb = o[2*b+1] - o[2*cc+1];
        float pred = 0.5f * (sqrtf(dxa*dxa + dya*dya) + sqrtf(dxb*dxb + dyb*dyb));
        float cxa = cg[2*a] - cg[2*b], cya = cg[2*a+1] - cg[2*b+1];
        float gxa = cg[2*b] - o[2*cc], gya = cg[2*b+1] - cg[2*cc+1];
        float gt = 0.5f * (sqrtf(cxa*cxa + cya*cya) + sqrtf(gxa*gxa + gya*gya));
        float vf = (cg[2*a] != -1.f && cg[2*b] != -1.f && cg[2*cc] != -1.f) ? 1.f : 0.f;
        float e = pred - gt;
        sp[p + 1] = e * e * vf; np[p + 1] = vf;
    }

    __syncthreads();   // all out-rows complete AND all f reads done (block-wide)

    // ---- coalesced x store (overwrites own f slice) + miss + kp-loss ----
    const size_t blkBase = (size_t)blockIdx.x * (NT * 36);
    const float4* cin4 = (const float4*)(cin + blkBase);
    const int4*   tm4  = (const int4*)(tmask + blkBase);
    float4*       x4   = (float4*)(xout + blkBase);
    float*        mo   = missout + blkBase;

    float s1 = 0.f, s2 = 0.f;
    #pragma unroll
    for (int i = 0; i < 9; ++i) {
        int g4 = i * NT + t;
        unsigned g = 4u * (unsigned)g4;
        unsigned row = g / 36u;
        unsigned col = g - row * 36u;          // %4 == 0 -> one 16B block
        float4 xv = *(const float4*)&sAB[lidx(row, col * 4u)];
        float4 cv = cin4[g4];
        int4   mv = tm4[g4];
        x4[g4] = xv;
        mo[g + 0] = (cv.x != -1.f) ? 1.f : 0.f;
        mo[g + 1] = (cv.y != -1.f) ? 1.f : 0.f;
        mo[g + 2] = (cv.z != -1.f) ? 1.f : 0.f;
        mo[g + 3] = (cv.w != -1.f) ? 1.f : 0.f;
        float m0 = (float)mv.x, m1_ = (float)mv.y, m2_ = (float)mv.z, m3_ = (float)mv.w;
        float d0 = xv.x - cv.x, d1 = xv.y - cv.y, d2 = xv.z - cv.z, d3 = xv.w - cv.w;
        s1 += d0*d0*m0 + d1*d1*m1_ + d2*d2*m2_ + d3*d3*m3_;
        s2 += m0 + m1_ + m2_ + m3_;
    }

    // ---- block reduction of 12 scalars ----
    float rv[12] = { s1, s2, sp[0], np[0], sp[1], np[1],
                     sp[2], np[2], sp[3], np[3], sp[4], np[4] };
    #pragma unroll
    for (int v = 0; v < 12; ++v) {
        #pragma unroll
        for (int off = 32; off > 0; off >>= 1)
            rv[v] += __shfl_down(rv[v], off, 64);
    }
    const int wave = t >> 6, lane6 = t & 63;
    if (lane6 == 0) {
        #pragma unroll
        for (int v = 0; v < 12; ++v) sred[wave][v] = rv[v];
    }
    __syncthreads();
    if (t < 12) {
        float s = sred[0][t] + sred[1][t] + sred[2][t] + sred[3][t];
        partials[blockIdx.x * 12 + t] = s;
    }
}

__global__ __launch_bounds__(256) void kp_fin(const float* __restrict__ partials,
                                              float* __restrict__ total_out)
{
    __shared__ float sred[4][12];
    const int t = threadIdx.x;
    float rv[12];
    #pragma unroll
    for (int v = 0; v < 12; ++v) rv[v] = 0.f;
    for (int b = t; b < NB; b += 256) {
        #pragma unroll
        for (int v = 0; v < 12; ++v) rv[v] += partials[b * 12 + v];
    }
    #pragma unroll
    for (int v = 0; v < 12; ++v) {
        #pragma unroll
        for (int off = 32; off > 0; off >>= 1)
            rv[v] += __shfl_down(rv[v], off, 64);
    }
    const int wave = t >> 6, lane = t & 63;
    if (lane == 0) {
        #pragma unroll
        for (int v = 0; v < 12; ++v) sred[wave][v] = rv[v];
    }
    __syncthreads();
    if (t == 0) {
        float acc[12];
        #pragma unroll
        for (int v = 0; v < 12; ++v)
            acc[v] = sred[0][v] + sred[1][v] + sred[2][v] + sred[3][v];
        float total = acc[0] / acc[1];
        #pragma unroll
        for (int p = 0; p < 5; ++p) {
            float s = acc[2 + 2 * p], n = acc[3 + 2 * p];
            total += (n > 0.f) ? (s / fmaxf(n, 1.f)) : 0.f;
        }
        total_out[0] = total;
    }
}

extern "C" void kernel_launch(void* const* d_in, const int* in_sizes, int n_in,
                              void* d_out, int out_size, void* d_ws, size_t ws_size,
                              hipStream_t stream)
{
    const float* cin   = (const float*)d_in[0];
    const int*   tmask = (const int*)  d_in[1];
    const float* w1  = (const float*)d_in[2];
    const float* b1  = (const float*)d_in[3];
    const float* g1  = (const float*)d_in[4];
    const float* bt1 = (const float*)d_in[5];
    const float* m1  = (const float*)d_in[6];
    const float* v1  = (const float*)d_in[7];
    const float* w2  = (const float*)d_in[8];
    const float* b2  = (const float*)d_in[9];
    const float* g2  = (const float*)d_in[10];
    const float* bt2 = (const float*)d_in[11];
    const float* m2  = (const float*)d_in[12];
    const float* v2  = (const float*)d_in[13];
    const float* w3  = (const float*)d_in[14];
    const float* b3  = (const float*)d_in[15];
    const float* g3  = (const float*)d_in[16];
    const float* bt3 = (const float*)d_in[17];
    const float* m3  = (const float*)d_in[18];
    const float* v3  = (const float*)d_in[19];
    const float* fw1 = (const float*)d_in[20];
    const float* fb1 = (const float*)d_in[21];
    const float* fw2 = (const float*)d_in[22];
    const float* fb2 = (const float*)d_in[23];

    float* xout     = (float*)d_out;                       // [B,36]; f staged per-block first
    float* total    = (float*)d_out + (size_t)BTOT * 36;   // scalar
    float* missout  = total + 1;                           // [B,36] as f32 0/1

    float* wsf      = (float*)d_ws;
    short* fr1      = (short*)((char*)d_ws + FR1_BYTE);
    short* fr2      = (short*)((char*)d_ws + FR2_BYTE);
    float* partials = (float*)((char*)d_ws + PART_BYTE);   // [NB,12]

    kp_setup<<<1, 256, 0, stream>>>(
        w1, b1, g1, bt1, m1, v1,
        w2, b2, g2, bt2, m2, v2,
        w3, b3, g3, bt3, m3, v3,
        fw1, fw2, wsf, fr1, fr2);

    kp_conv<<<NB, NT, 0, stream>>>(cin, wsf, xout);

    kp_fc<<<NB, NT, 0, stream>>>(cin, tmask, fr1, fr2,
        fb1, fb2, xout, missout, partials);

    kp_fin<<<1, 256, 0, stream>>>(partials, total);
}

// Round 10
// 77.408 us; speedup vs baseline: 2.0648x; 1.3128x over previous
//
#include <hip/hip_runtime.h>

#define NB   1024
#define NT   256
#define BTOT 262144   // NB*NT == B

typedef __attribute__((ext_vector_type(8))) short short8;
typedef __attribute__((ext_vector_type(4))) float f32x4;

__device__ __forceinline__ float relu_(float x) { return fmaxf(x, 0.0f); }

__device__ __forceinline__ short f2bf(float x) {   // RNE f32->bf16
    unsigned u = __float_as_uint(x);
    return (short)((u + 0x7FFFu + ((u >> 16) & 1u)) >> 16);
}
__device__ __forceinline__ unsigned pk2bf(float a, float b) {
    return ((unsigned)(unsigned short)f2bf(a)) |
           (((unsigned)(unsigned short)f2bf(b)) << 16);
}

// d_ws byte map:
//  0    : bias cols  bc1[32] | bc2[64] | bc3[64]  (f32, 160 floats)
//  640  : A0 packed bf16 pairs (5 dwords used)
//  768  : 46 B-fragments x 512 shorts (bf16):
//         B1: frag 0..3   (conv1, nt<2, kt<2)
//         B2: frag 4..11  (conv2, nt<4, kt<2)
//         B3: frag 12..19 (conv3, nt<4, kt<2)
//         F1: frag 20..33 (fc1,   n<7,  kt<2)
//         F2: frag 34..45 (fc2,   n<3,  kt<4)
//  47872: partials [NB*12] f32
#define A0_DW    160
#define FRAGS_BYTE 768
#define PART_BYTE 47872
#define NFRAG 46

__global__ __launch_bounds__(256) void kp_setup(
    const float* __restrict__ w1, const float* __restrict__ b1,
    const float* __restrict__ g1, const float* __restrict__ bt1,
    const float* __restrict__ m1, const float* __restrict__ v1,
    const float* __restrict__ w2, const float* __restrict__ b2,
    const float* __restrict__ g2, const float* __restrict__ bt2,
    const float* __restrict__ m2, const float* __restrict__ v2,
    const float* __restrict__ w3, const float* __restrict__ b3,
    const float* __restrict__ g3, const float* __restrict__ bt3,
    const float* __restrict__ m3, const float* __restrict__ v3,
    const float* __restrict__ fw1, const float* __restrict__ fw2,
    float* __restrict__ wsB, short* __restrict__ frags)
{
    __shared__ float w1f[180], b1f[10], a0f[10];
    __shared__ float w2f[400], b2f[20];
    __shared__ float w3f[1200], b3f[30];
    const int t = threadIdx.x;

    if (t < 10) {
        float s = g1[t] * rsqrtf(v1[t] + 1e-5f);
        float bb = (b1[t] - m1[t]) * s + bt1[t];
        b1f[t] = bb; a0f[t] = relu_(bb);
        for (int i = 0; i < 18; ++i) w1f[t * 18 + i] = w1[t * 18 + i] * s;
    } else if (t >= 64 && t < 84) {
        int o = t - 64;
        float s = g2[o] * rsqrtf(v2[o] + 1e-5f);
        b2f[o] = (b2[o] - m2[o]) * s + bt2[o];
        for (int i = 0; i < 20; ++i) w2f[o * 20 + i] = w2[o * 20 + i] * s;
    } else if (t >= 128 && t < 158) {
        int o = t - 128;
        float s = g3[o] * rsqrtf(v3[o] + 1e-5f);
        b3f[o] = (b3[o] - m3[o]) * s + bt3[o];
        for (int i = 0; i < 40; ++i) w3f[o * 40 + i] = w3[o * 40 + i] * s;
    }
    __syncthreads();

    if (blockIdx.x == 0) {
        if (t < 32)        { int n = t;      wsB[n]      = (n < 20) ? b1f[n % 10] : 0.f; }
        else if (t < 96)   { int n = t - 32; wsB[32 + n] = (n < 60) ? b2f[n % 20] : 0.f; }
        else if (t < 160)  { int n = t - 96; wsB[96 + n] = (n < 60) ? b3f[n % 30] : 0.f; }
        else if (t < 165)  { int q = t - 160; ((unsigned*)wsB)[A0_DW + q] = pk2bf(a0f[2*q], a0f[2*q+1]); }
    }

    for (int e = blockIdx.x * 256 + t; e < NFRAG * 512; e += gridDim.x * 256) {
        int frag = e >> 9, l = (e >> 3) & 63, j = e & 7;
        float val = 0.f;
        if (frag < 4) {
            int p = frag, nt = p >> 1, kt = p & 1;
            int k = kt * 32 + (l >> 4) * 8 + j, n = nt * 16 + (l & 15);
            if (k < 36 && n < 20) {
                int i = k >> 1, s = k & 1, pp = n / 10, o = n % 10;
                if (s == pp) val = w1f[o * 18 + i];
            }
        } else if (frag < 12) {
            int p = frag - 4, nt = p >> 1, kt = p & 1;
            int k = kt * 32 + (l >> 4) * 8 + j, n = nt * 16 + (l & 15);
            if (k < 40 && n < 60) {
                int pp = k / 10, i = k % 10, q = n / 20, o = n % 20, d = pp - q;
                if (d == 0 || d == 1) val = w2f[o * 20 + i * 2 + d];
            }
        } else if (frag < 20) {
            int p = frag - 12, nt = p >> 1, kt = p & 1;
            int k = kt * 32 + (l >> 4) * 8 + j, n = nt * 16 + (l & 15);
            if (k < 60 && n < 60) {
                int pp = k / 20, i = k % 20, q = n / 30, o = n % 30, d = pp - q;
                if (d == 0 || d == 1) val = w3f[o * 40 + i * 2 + d];
            }
        } else if (frag < 34) {
            int p = frag - 20, n7 = p >> 1, kt = p & 1;
            int k = kt * 32 + (l >> 4) * 8 + j, col = n7 * 16 + (l & 15);
            if (col < 100 && k < 60) val = fw1[col * 60 + k];
        } else {
            int p = frag - 34, n3 = p >> 2, kt = p & 3;
            int k = kt * 32 + (l >> 4) * 8 + j, col = n3 * 16 + (l & 15);
            if (col < 36 && k < 100) val = fw2[col * 100 + k];
        }
        frags[e] = f2bf(val);
    }
}

__global__ __launch_bounds__(NT) void kp_main(
    const float* __restrict__ cin, const int* __restrict__ tmask,
    const float* __restrict__ wsB, const short* __restrict__ frags,
    const float* __restrict__ fb1, const float* __restrict__ fb2,
    float* __restrict__ xout, float* __restrict__ missout,
    float* __restrict__ partials)
{
    __shared__ __align__(16) unsigned char sOUT[NT * 144];      // c rows -> out rows
    __shared__ __align__(16) unsigned char sT1[4 * 16 * 144];   // a1 (pad zeros persist)
    __shared__ __align__(16) unsigned char sT2[4 * 16 * 144];   // a2 -> f -> z
    __shared__ float sred[4][12];

    const int t = threadIdx.x;
    const int tid = blockIdx.x * NT + t;
    const float* cp = cin + (size_t)tid * 36;
    const int lane = t & 63, wave = t >> 6;
    const unsigned lrow = (unsigned)(lane & 15);
    const unsigned lkg  = (unsigned)(lane >> 4);
    const unsigned wbase = (unsigned)(t & ~63);
    const short8* frg = (const short8*)frags;

    // ---- prologue: c -> own sOUT row as bf16 (stride 144, zero pad) ----
    {
        float c[36];
        #pragma unroll
        for (int i = 0; i < 9; ++i)
            *(float4*)(c + 4 * i) = *(const float4*)(cp + 4 * i);
        unsigned d[18];
        #pragma unroll
        for (int j = 0; j < 18; ++j) d[j] = pk2bf(c[2 * j], c[2 * j + 1]);
        uint4* rp = (uint4*)&sOUT[t * 144];
        rp[0] = make_uint4(d[0], d[1], d[2], d[3]);
        rp[1] = make_uint4(d[4], d[5], d[6], d[7]);
        rp[2] = make_uint4(d[8], d[9], d[10], d[11]);
        rp[3] = make_uint4(d[12], d[13], d[14], d[15]);
        rp[4] = make_uint4(d[16], d[17], 0u, 0u);
        rp[5] = make_uint4(0u, 0u, 0u, 0u);
        rp[6] = rp[5]; rp[7] = rp[5]; rp[8] = rp[5];
    }
    // zero this wave's sT1/sT2 rows once (pad bytes must start zero)
    if (lane < 32) {
        unsigned char* base = (lane < 16 ? sT1 : sT2) + ((wave * 16 + (lane & 15)) * 144);
        uint4 z = make_uint4(0u, 0u, 0u, 0u);
        #pragma unroll
        for (int q = 0; q < 9; ++q) ((uint4*)base)[q] = z;
    }

    // ---- per-lane uniforms ----
    float bc1v[2], bc2v[4], bc3v[4], fb1v[7], fb2v[3];
    #pragma unroll
    for (int nt = 0; nt < 2; ++nt) bc1v[nt] = wsB[nt * 16 + (int)lrow];
    #pragma unroll
    for (int nt = 0; nt < 4; ++nt) bc2v[nt] = wsB[32 + nt * 16 + (int)lrow];
    #pragma unroll
    for (int nt = 0; nt < 4; ++nt) bc3v[nt] = wsB[96 + nt * 16 + (int)lrow];
    #pragma unroll
    for (int n = 0; n < 7; ++n) { int j = 16 * n + (int)lrow; fb1v[n] = (j < 100) ? fb1[j] : 0.f; }
    #pragma unroll
    for (int n = 0; n < 3; ++n) { int cc = 16 * n + (int)lrow; fb2v[n] = (cc < 36) ? fb2[cc] : 0.f; }
    const unsigned* a0p = (const unsigned*)wsB + A0_DW;
    uint4 A0q = *(const uint4*)a0p;
    unsigned A0e = a0p[4];

    unsigned char* T1 = sT1 + (wave * 16) * 144;   // tile-local rows 0..15
    unsigned char* T2 = sT2 + (wave * 16) * 144;

    #pragma unroll 1
    for (int m = 0; m < 4; ++m) {
        const unsigned Rb = wbase + 16u * (unsigned)m;

        // ---- conv1: A = c rows (sOUT), D -> a1 (sT1) ----
        short8 Aa = *(const short8*)&sOUT[(Rb + lrow) * 144 + lkg * 16u];
        short8 Ab = *(const short8*)&sOUT[(Rb + lrow) * 144 + 64u + lkg * 16u];
        {
            f32x4 D1[2];
            #pragma unroll
            for (int nt = 0; nt < 2; ++nt) {
                D1[nt] = (f32x4){0.f, 0.f, 0.f, 0.f};
                D1[nt] = __builtin_amdgcn_mfma_f32_16x16x32_bf16(Aa, frg[(0 + nt * 2 + 0) * 64 + lane], D1[nt], 0, 0, 0);
                D1[nt] = __builtin_amdgcn_mfma_f32_16x16x32_bf16(Ab, frg[(0 + nt * 2 + 1) * 64 + lane], D1[nt], 0, 0, 0);
            }
            #pragma unroll
            for (int nt = 0; nt < 2; ++nt) {
                int n1 = nt * 16 + (int)lrow;
                if (n1 < 20) {
                    #pragma unroll
                    for (int i = 0; i < 4; ++i)
                        *(short*)&T1[(4 * lkg + i) * 144 + (n1 + 10) * 2] =
                            f2bf(relu_(D1[nt][i] + bc1v[nt]));
                }
            }
        }
        // A0 constants into a1 rows (pos0: k 0..9, pos3: k 30..39)
        if (lane < 16) {
            unsigned char* b = &T1[(unsigned)lane * 144];
            *(uint4*)(b + 0) = A0q;
            *(unsigned*)(b + 16) = A0e;
        } else if (lane < 32) {
            unsigned char* b = &T1[(unsigned)(lane - 16) * 144];
            *(unsigned*)(b + 60) = A0q.x;
            *(uint4*)(b + 64) = make_uint4(A0q.y, A0q.z, A0q.w, A0e);
        }

        // ---- conv2: A = a1 (sT1), D -> a2 (sT2, full row rewrite) ----
        Aa = *(const short8*)&T1[lrow * 144 + lkg * 16u];
        Ab = *(const short8*)&T1[lrow * 144 + 64u + lkg * 16u];
        {
            f32x4 D2[4];
            #pragma unroll
            for (int nt = 0; nt < 4; ++nt) {
                D2[nt] = (f32x4){0.f, 0.f, 0.f, 0.f};
                D2[nt] = __builtin_amdgcn_mfma_f32_16x16x32_bf16(Aa, frg[(4 + nt * 2 + 0) * 64 + lane], D2[nt], 0, 0, 0);
                D2[nt] = __builtin_amdgcn_mfma_f32_16x16x32_bf16(Ab, frg[(4 + nt * 2 + 1) * 64 + lane], D2[nt], 0, 0, 0);
            }
            #pragma unroll
            for (int nt = 0; nt < 4; ++nt) {
                int n2 = nt * 16 + (int)lrow;
                #pragma unroll
                for (int i = 0; i < 4; ++i)
                    *(short*)&T2[(4 * lkg + i) * 144 + n2 * 2] =
                        f2bf(relu_(D2[nt][i] + bc2v[nt]));
            }
        }

        // ---- conv3: A = a2 (sT2), D -> f (sT2, kf = 2*(n%30)+n/30) ----
        Aa = *(const short8*)&T2[lrow * 144 + lkg * 16u];
        Ab = *(const short8*)&T2[lrow * 144 + 64u + lkg * 16u];
        {
            f32x4 D3[4];
            #pragma unroll
            for (int nt = 0; nt < 4; ++nt) {
                D3[nt] = (f32x4){0.f, 0.f, 0.f, 0.f};
                D3[nt] = __builtin_amdgcn_mfma_f32_16x16x32_bf16(Aa, frg[(12 + nt * 2 + 0) * 64 + lane], D3[nt], 0, 0, 0);
                D3[nt] = __builtin_amdgcn_mfma_f32_16x16x32_bf16(Ab, frg[(12 + nt * 2 + 1) * 64 + lane], D3[nt], 0, 0, 0);
            }
            #pragma unroll
            for (int nt = 0; nt < 4; ++nt) {
                int n3 = nt * 16 + (int)lrow;
                if (n3 < 60) {
                    int o = (n3 >= 30) ? n3 - 30 : n3;
                    int kf = 2 * o + (n3 >= 30 ? 1 : 0);
                    #pragma unroll
                    for (int i = 0; i < 4; ++i)
                        *(short*)&T2[(4 * lkg + i) * 144 + kf * 2] =
                            f2bf(relu_(D3[nt][i] + bc3v[nt]));
                }
            }
        }

        // ---- fc1 + fc2 (A = f in sT2; z halves overwrite sT2) ----
        short8 Fa = *(const short8*)&T2[lrow * 144 + lkg * 16u];
        short8 Fb = *(const short8*)&T2[lrow * 144 + 64u + lkg * 16u];
        f32x4 acc2[3];
        #pragma unroll
        for (int n = 0; n < 3; ++n) acc2[n] = (f32x4){0.f, 0.f, 0.f, 0.f};

        #pragma unroll
        for (int h = 0; h < 2; ++h) {
            f32x4 acc1[4];
            #pragma unroll
            for (int nn = 0; nn < 4; ++nn) {
                const int n = 4 * h + nn;
                acc1[nn] = (f32x4){0.f, 0.f, 0.f, 0.f};
                if (n < 7) {
                    acc1[nn] = __builtin_amdgcn_mfma_f32_16x16x32_bf16(Fa, frg[(20 + n * 2 + 0) * 64 + lane], acc1[nn], 0, 0, 0);
                    acc1[nn] = __builtin_amdgcn_mfma_f32_16x16x32_bf16(Fb, frg[(20 + n * 2 + 1) * 64 + lane], acc1[nn], 0, 0, 0);
                }
            }
            #pragma unroll
            for (int nn = 0; nn < 4; ++nn) {
                const int n = 4 * h + nn;
                #pragma unroll
                for (int i = 0; i < 4; ++i) {
                    float zv = (n < 7) ? relu_(acc1[nn][i] + fb1v[n]) : 0.f;
                    *(short*)&T2[(4 * lkg + i) * 144 + (16 * nn + (int)lrow) * 2] = f2bf(zv);
                }
            }
            #pragma unroll
            for (int q = 0; q < 2; ++q) {
                const int kt = 2 * h + q;
                short8 Az = *(const short8*)&T2[lrow * 144 + (unsigned)(q * 64) + lkg * 16u];
                #pragma unroll
                for (int n = 0; n < 3; ++n)
                    acc2[n] = __builtin_amdgcn_mfma_f32_16x16x32_bf16(Az, frg[(34 + n * 4 + kt) * 64 + lane], acc2[n], 0, 0, 0);
            }
        }

        // out (f32) -> sOUT rows of this tile
        #pragma unroll
        for (int n = 0; n < 3; ++n) {
            const int col = 16 * n + (int)lrow;
            if (col < 36) {
                #pragma unroll
                for (int i = 0; i < 4; ++i)
                    *(float*)&sOUT[(Rb + 4 * lkg + i) * 144 + col * 4] = acc2[n][i] + fb2v[n];
            }
        }
    }

    // ---- per-sample part losses: own out-row + c reload (L2-hot) ----
    float cg[32];
    #pragma unroll
    for (int i = 0; i < 8; ++i)
        *(float4*)(cg + 4 * i) = *(const float4*)(cp + 4 * i);

    float o[32];
    #pragma unroll
    for (int b = 0; b < 8; ++b) {
        float4 v = *(const float4*)&sOUT[t * 144 + b * 16];
        o[4 * b + 0] = v.x; o[4 * b + 1] = v.y; o[4 * b + 2] = v.z; o[4 * b + 3] = v.w;
    }

    float sp[5], np[5];
    {   // head (0,14,15); gt mixes x[:,15,0] and c[:,15,1] (faithful)
        float dxa = o[0] - o[28], dya = o[1] - o[29];
        float dxb = o[0] - o[30], dyb = o[1] - o[31];
        float pred = 0.5f * (sqrtf(dxa*dxa + dya*dya) + sqrtf(dxb*dxb + dyb*dyb));
        float cxa = cg[0] - cg[28], cya = cg[1] - cg[29];
        float gxa = cg[0] - o[30],  gya = cg[1] - cg[31];
        float gt = 0.5f * (sqrtf(cxa*cxa + cya*cya) + sqrtf(gxa*gxa + gya*gya));
        float vf = (cg[0] != -1.f && cg[28] != -1.f && cg[30] != -1.f) ? 1.f : 0.f;
        float e = pred - gt;
        sp[0] = e * e * vf; np[0] = vf;
    }
    #pragma unroll
    for (int p = 0; p < 4; ++p) {
        const int a = 2 + 3 * p, b = a + 1, cc = a + 2;
        float dxa = o[2*a] - o[2*b],  dya = o[2*a+1] - o[2*b+1];
        float dxb = o[2*b] - o[2*cc], dyb = o[2*b+1] - o[2*cc+1];
        float pred = 0.5f * (sqrtf(dxa*dxa + dya*dya) + sqrtf(dxb*dxb + dyb*dyb));
        float cxa = cg[2*a] - cg[2*b], cya = cg[2*a+1] - cg[2*cc-2+1];
        // NOTE: cya must be cg[2a+1]-cg[2b+1]; write explicitly below
        cya = cg[2*a+1] - cg[2*b+1];
        float gxa = cg[2*b] - o[2*cc], gya = cg[2*b+1] - cg[2*cc+1];
        float gt = 0.5f * (sqrtf(cxa*cxa + cya*cya) + sqrtf(gxa*gxa + gya*gya));
        float vf = (cg[2*a] != -1.f && cg[2*b] != -1.f && cg[2*cc] != -1.f) ? 1.f : 0.f;
        float e = pred - gt;
        sp[p + 1] = e * e * vf; np[p + 1] = vf;
    }

    __syncthreads();   // all waves' out-rows complete

    // ---- coalesced x store + miss store + elementwise kp-loss ----
    const size_t blkBase = (size_t)blockIdx.x * (NT * 36);
    const float4* cin4 = (const float4*)(cin + blkBase);
    const int4*   tm4  = (const int4*)(tmask + blkBase);
    float4*       x4   = (float4*)(xout + blkBase);
    float*        mo   = missout + blkBase;

    float s1 = 0.f, s2 = 0.f;
    #pragma unroll
    for (int i = 0; i < 9; ++i) {
        int g4 = i * NT + t;
        unsigned g = 4u * (unsigned)g4;
        unsigned row = g / 36u;
        unsigned col = g - row * 36u;
        float4 xv = *(const float4*)&sOUT[row * 144u + col * 4u];
        float4 cv = cin4[g4];
        int4   mv = tm4[g4];
        x4[g4] = xv;
        mo[g + 0] = (cv.x != -1.f) ? 1.f : 0.f;
        mo[g + 1] = (cv.y != -1.f) ? 1.f : 0.f;
        mo[g + 2] = (cv.z != -1.f) ? 1.f : 0.f;
        mo[g + 3] = (cv.w != -1.f) ? 1.f : 0.f;
        float m0 = (float)mv.x, m1_ = (float)mv.y, m2_ = (float)mv.z, m3_ = (float)mv.w;
        float d0 = xv.x - cv.x, d1 = xv.y - cv.y, d2 = xv.z - cv.z, d3 = xv.w - cv.w;
        s1 += d0*d0*m0 + d1*d1*m1_ + d2*d2*m2_ + d3*d3*m3_;
        s2 += m0 + m1_ + m2_ + m3_;
    }

    float rv[12] = { s1, s2, sp[0], np[0], sp[1], np[1],
                     sp[2], np[2], sp[3], np[3], sp[4], np[4] };
    #pragma unroll
    for (int v = 0; v < 12; ++v) {
        #pragma unroll
        for (int off = 32; off > 0; off >>= 1)
            rv[v] += __shfl_down(rv[v], off, 64);
    }
    const int lane6 = t & 63;
    if (lane6 == 0) {
        #pragma unroll
        for (int v = 0; v < 12; ++v) sred[wave][v] = rv[v];
    }
    __syncthreads();
    if (t < 12) {
        float s = sred[0][t] + sred[1][t] + sred[2][t] + sred[3][t];
        partials[blockIdx.x * 12 + t] = s;
    }
}

__global__ __launch_bounds__(256) void kp_fin(const float* __restrict__ partials,
                                              float* __restrict__ total_out)
{
    __shared__ float sred[4][12];
    const int t = threadIdx.x;
    float rv[12];
    #pragma unroll
    for (int v = 0; v < 12; ++v) rv[v] = 0.f;
    for (int b = t; b < NB; b += 256) {
        #pragma unroll
        for (int v = 0; v < 12; ++v) rv[v] += partials[b * 12 + v];
    }
    #pragma unroll
    for (int v = 0; v < 12; ++v) {
        #pragma unroll
        for (int off = 32; off > 0; off >>= 1)
            rv[v] += __shfl_down(rv[v], off, 64);
    }
    const int wave = t >> 6, lane = t & 63;
    if (lane == 0) {
        #pragma unroll
        for (int v = 0; v < 12; ++v) sred[wave][v] = rv[v];
    }
    __syncthreads();
    if (t == 0) {
        float acc[12];
        #pragma unroll
        for (int v = 0; v < 12; ++v)
            acc[v] = sred[0][v] + sred[1][v] + sred[2][v] + sred[3][v];
        float total = acc[0] / acc[1];
        #pragma unroll
        for (int p = 0; p < 5; ++p) {
            float s = acc[2 + 2 * p], n = acc[3 + 2 * p];
            total += (n > 0.f) ? (s / fmaxf(n, 1.f)) : 0.f;
        }
        total_out[0] = total;
    }
}

extern "C" void kernel_launch(void* const* d_in, const int* in_sizes, int n_in,
                              void* d_out, int out_size, void* d_ws, size_t ws_size,
                              hipStream_t stream)
{
    const float* cin   = (const float*)d_in[0];
    const int*   tmask = (const int*)  d_in[1];
    const float* w1  = (const float*)d_in[2];
    const float* b1  = (const float*)d_in[3];
    const float* g1  = (const float*)d_in[4];
    const float* bt1 = (const float*)d_in[5];
    const float* m1  = (const float*)d_in[6];
    const float* v1  = (const float*)d_in[7];
    const float* w2  = (const float*)d_in[8];
    const float* b2  = (const float*)d_in[9];
    const float* g2  = (const float*)d_in[10];
    const float* bt2 = (const float*)d_in[11];
    const float* m2  = (const float*)d_in[12];
    const float* v2  = (const float*)d_in[13];
    const float* w3  = (const float*)d_in[14];
    const float* b3  = (const float*)d_in[15];
    const float* g3  = (const float*)d_in[16];
    const float* bt3 = (const float*)d_in[17];
    const float* m3  = (const float*)d_in[18];
    const float* v3  = (const float*)d_in[19];
    const float* fw1 = (const float*)d_in[20];
    const float* fb1 = (const float*)d_in[21];
    const float* fw2 = (const float*)d_in[22];
    const float* fb2 = (const float*)d_in[23];

    float* xout     = (float*)d_out;                       // [B,36]
    float* total    = (float*)d_out + (size_t)BTOT * 36;   // scalar
    float* missout  = total + 1;                           // [B,36] as f32 0/1

    float* wsB      = (float*)d_ws;
    short* frags    = (short*)((char*)d_ws + FRAGS_BYTE);
    float* partials = (float*)((char*)d_ws + PART_BYTE);   // [NB,12]

    kp_setup<<<8, 256, 0, stream>>>(
        w1, b1, g1, bt1, m1, v1,
        w2, b2, g2, bt2, m2, v2,
        w3, b3, g3, bt3, m3, v3,
        fw1, fw2, wsB, frags);

    kp_main<<<NB, NT, 0, stream>>>(cin, tmask, wsB, frags,
        fb1, fb2, xout, missout, partials);

    kp_fin<<<1, 256, 0, stream>>>(partials, total);
}